// Round 9
// baseline (419.709 us; speedup 1.0000x reference)
//
#include <hip/hip_runtime.h>
#include <math.h>

// Problem constants
#define BATCH 2
#define SEQ 2048
#define DMODEL 2048
#define NHEADS 16
#define HEADDIM 128
#define MTOT (BATCH * SEQ)   // 4096
#define QKVLD 6144           // fused QKV row stride (Q|K|V)

typedef __attribute__((ext_vector_type(8))) _Float16 half8;  // 8 f16 (4 VGPRs)
typedef __attribute__((ext_vector_type(4))) _Float16 half4;  // 4 f16 (2 VGPRs)
typedef __attribute__((ext_vector_type(4))) float f32x4;     // 4 fp32

// async global -> LDS, 16B per lane (global_load_lds_dwordx4)
__device__ __forceinline__ void gl_lds16(const void* g, void* l) {
    __builtin_amdgcn_global_load_lds(
        (const __attribute__((address_space(1))) unsigned int*)g,
        (__attribute__((address_space(3))) unsigned int*)l, 16, 0, 0);
}

// ---------------------------------------------------------------------------
// fp32 -> f16 convert, 8 elems/thread; query + Wq + Wk + Wv in ONE dispatch.
// blocks [0, 4096): query -> xh ; [4096, 10240): Wq/Wk/Wv -> Wh3 slots
// ---------------------------------------------------------------------------
__global__ __launch_bounds__(256) void f2h_multi(const float* __restrict__ query,
                                                 const float* __restrict__ Wq,
                                                 const float* __restrict__ Wk,
                                                 const float* __restrict__ Wv,
                                                 _Float16* __restrict__ xh,
                                                 _Float16* __restrict__ Wh3) {
    const float* src;
    _Float16* dst;
    size_t i;
    int bx = blockIdx.x;
    if (bx < 4096) {
        src = query; dst = xh;
        i = ((size_t)bx * 256 + threadIdx.x) * 8;
    } else {
        int wi = bx - 4096;
        int y = wi >> 11;           // 0..2
        int off = wi & 2047;
        src = (y == 0) ? Wq : (y == 1) ? Wk : Wv;
        dst = Wh3 + (size_t)y * (DMODEL * DMODEL);
        i = ((size_t)off * 256 + threadIdx.x) * 8;
    }
    float4 a = *(const float4*)(src + i);
    float4 b = *(const float4*)(src + i + 4);
    union { uint4 u; _Float16 h[8]; } o;
    o.h[0] = (_Float16)a.x; o.h[1] = (_Float16)a.y;
    o.h[2] = (_Float16)a.z; o.h[3] = (_Float16)a.w;
    o.h[4] = (_Float16)b.x; o.h[5] = (_Float16)b.y;
    o.h[6] = (_Float16)b.z; o.h[7] = (_Float16)b.w;
    *(uint4*)(dst + i) = o.u;
}

// plain single-source convert (for Wo)
__global__ __launch_bounds__(256) void f2h_conv(const float* __restrict__ src,
                                                _Float16* __restrict__ dst) {
    size_t i = ((size_t)blockIdx.x * 256 + threadIdx.x) * 8;
    float4 a = *(const float4*)(src + i);
    float4 b = *(const float4*)(src + i + 4);
    union { uint4 u; _Float16 h[8]; } o;
    o.h[0] = (_Float16)a.x; o.h[1] = (_Float16)a.y;
    o.h[2] = (_Float16)a.z; o.h[3] = (_Float16)a.w;
    o.h[4] = (_Float16)b.x; o.h[5] = (_Float16)b.y;
    o.h[6] = (_Float16)b.z; o.h[7] = (_Float16)b.w;
    *(uint4*)(dst + i) = o.u;
}

// ---------------------------------------------------------------------------
// 8-phase 256x256 MFMA GEMM (for the large QKV projection).
// BK=64, 8 waves (2Mx4N), double-buffered LDS, XOR-swizzled LDS reads,
// counted vmcnt(4) at phases 4/8, setprio around MFMA clusters.
// ---------------------------------------------------------------------------
#define SB0  __builtin_amdgcn_sched_barrier(0)
#define BAR  __builtin_amdgcn_s_barrier()
#define VMW4 do { SB0; asm volatile("s_waitcnt vmcnt(4)"); SB0; } while (0)
#define VMW0 do { SB0; asm volatile("s_waitcnt vmcnt(0)"); SB0; } while (0)

template <bool F16OUT>
__global__ __launch_bounds__(512, 2) void gemm8p(const _Float16* __restrict__ A,
                                                 const _Float16* __restrict__ W,
                                                 void* __restrict__ Cout,
                                                 int M, int N, int K) {
    __shared__ __align__(16) _Float16 LAb[2][2][128][64];  // 64 KB
    __shared__ __align__(16) _Float16 LBb[2][2][128][64];  // 64 KB

    const int tid = threadIdx.x;
    const int lane = tid & 63;
    const int wave = tid >> 6;
    const int quad = lane >> 4;
    const int lcol = lane & 15;
    const int wr = wave >> 2;    // 0..1  (M half)
    const int wc = wave & 3;     // 0..3  (N quarter)
    const int m0 = blockIdx.y * 256;
    const int n0 = blockIdx.x * 256;

    const int srow = tid >> 3;                // 0..63
    const int sc8p = tid & 7;                 // physical 16B chunk (linear LDS)
    const int sc8l = sc8p ^ (srow & 7);       // logical chunk (pre-swizzled src)

#define STA(BUF, HALF, KT)                                                     \
    do {                                                                       \
        _Pragma("unroll") for (int j = 0; j < 2; j++)                          \
            gl_lds16(A + (size_t)(m0 + (HALF)*128 + j*64 + srow) * K +         \
                         (KT)*64 + sc8l*8,                                     \
                     &LAb[BUF][HALF][j*64 + srow][sc8p*8]);                    \
    } while (0)
#define STB(BUF, HALF, KT)                                                     \
    do {                                                                       \
        _Pragma("unroll") for (int j = 0; j < 2; j++)                          \
            gl_lds16(W + (size_t)(n0 + (HALF)*128 + j*64 + srow) * K +         \
                         (KT)*64 + sc8l*8,                                     \
                     &LBb[BUF][HALF][j*64 + srow][sc8p*8]);                    \
    } while (0)

    auto rdA = [&](int buf, int mf, int ks) -> half8 {
        int R = mf * 16 + lcol;
        return *(const half8*)&LAb[buf][wr][R]
                [(ks * 32 + quad * 8) ^ ((lcol & 7) << 3)];
    };
    auto rdB = [&](int buf, int nf, int ks) -> half8 {
        int R = (wc & 1) * 64 + nf * 16 + lcol;
        return *(const half8*)&LBb[buf][wc >> 1][R]
                [(ks * 32 + quad * 8) ^ ((lcol & 7) << 3)];
    };

    f32x4 acc[8][4];
#pragma unroll
    for (int i = 0; i < 8; i++)
#pragma unroll
        for (int j = 0; j < 4; j++) acc[i][j] = (f32x4){0.f, 0.f, 0.f, 0.f};

#define KTILE4(BUF, S1, S2, S3, S4, W4)                                        \
    {                                                                          \
        half8 a[4][2], b[4][2];                                                \
        _Pragma("unroll") for (int mf = 0; mf < 4; mf++)                       \
            _Pragma("unroll") for (int ks = 0; ks < 2; ks++)                   \
                a[mf][ks] = rdA(BUF, mf, ks);                                  \
        _Pragma("unroll") for (int nf = 0; nf < 2; nf++)                       \
            _Pragma("unroll") for (int ks = 0; ks < 2; ks++)                   \
                b[nf][ks] = rdB(BUF, nf, ks);                                  \
        S1; SB0; BAR; SB0;                                                     \
        __builtin_amdgcn_s_setprio(1);                                         \
        _Pragma("unroll") for (int ks = 0; ks < 2; ks++)                       \
            _Pragma("unroll") for (int mf = 0; mf < 4; mf++)                   \
                _Pragma("unroll") for (int nf = 0; nf < 2; nf++)               \
                    acc[mf][nf] = __builtin_amdgcn_mfma_f32_16x16x32_f16(      \
                        a[mf][ks], b[nf][ks], acc[mf][nf], 0, 0, 0);           \
        __builtin_amdgcn_s_setprio(0); SB0; BAR; SB0;                          \
        _Pragma("unroll") for (int nf = 0; nf < 2; nf++)                       \
            _Pragma("unroll") for (int ks = 0; ks < 2; ks++)                   \
                b[2 + nf][ks] = rdB(BUF, 2 + nf, ks);                          \
        S2; SB0; BAR; SB0;                                                     \
        __builtin_amdgcn_s_setprio(1);                                         \
        _Pragma("unroll") for (int ks = 0; ks < 2; ks++)                       \
            _Pragma("unroll") for (int mf = 0; mf < 4; mf++)                   \
                _Pragma("unroll") for (int nf = 0; nf < 2; nf++)               \
                    acc[mf][2 + nf] = __builtin_amdgcn_mfma_f32_16x16x32_f16(  \
                        a[mf][ks], b[2 + nf][ks], acc[mf][2 + nf], 0, 0, 0);   \
        __builtin_amdgcn_s_setprio(0); SB0; BAR; SB0;                          \
        _Pragma("unroll") for (int mf = 0; mf < 4; mf++)                       \
            _Pragma("unroll") for (int ks = 0; ks < 2; ks++)                   \
                a[mf][ks] = rdA(BUF, 4 + mf, ks);                              \
        S3; SB0; BAR; SB0;                                                     \
        __builtin_amdgcn_s_setprio(1);                                         \
        _Pragma("unroll") for (int ks = 0; ks < 2; ks++)                       \
            _Pragma("unroll") for (int mf = 0; mf < 4; mf++)                   \
                _Pragma("unroll") for (int nf = 0; nf < 2; nf++)               \
                    acc[4 + mf][nf] = __builtin_amdgcn_mfma_f32_16x16x32_f16(  \
                        a[mf][ks], b[nf][ks], acc[4 + mf][nf], 0, 0, 0);       \
        __builtin_amdgcn_s_setprio(0); SB0; BAR; SB0;                          \
        S4; W4; BAR; SB0;                                                      \
        __builtin_amdgcn_s_setprio(1);                                         \
        _Pragma("unroll") for (int ks = 0; ks < 2; ks++)                       \
            _Pragma("unroll") for (int mf = 0; mf < 4; mf++)                   \
                _Pragma("unroll") for (int nf = 0; nf < 2; nf++)               \
                    acc[4 + mf][2 + nf] =                                      \
                        __builtin_amdgcn_mfma_f32_16x16x32_f16(                \
                            a[mf][ks], b[2 + nf][ks], acc[4 + mf][2 + nf],     \
                            0, 0, 0);                                          \
        __builtin_amdgcn_s_setprio(0); SB0; BAR; SB0;                          \
    }

    STB(0, 0, 0); STB(0, 1, 0); STA(0, 0, 0); STA(0, 1, 0);
    STB(1, 0, 1); STB(1, 1, 1);
    VMW4; BAR; SB0;

    const int niter = K >> 7;  // K/128 (2 K-tiles per iteration)
    for (int i = 0; i < niter - 1; ++i) {
        const int t0 = 2 * i;
        KTILE4(0, STA(1, 0, t0 + 1), STA(1, 1, t0 + 1),
                  STB(0, 0, t0 + 2), STB(0, 1, t0 + 2), VMW4);
        KTILE4(1, STA(0, 0, t0 + 2), STA(0, 1, t0 + 2),
                  STB(1, 0, t0 + 3), STB(1, 1, t0 + 3), VMW4);
    }
    {
        const int t0 = 2 * (niter - 1);
        KTILE4(0, STA(1, 0, t0 + 1), STA(1, 1, t0 + 1),
                  (void)0, (void)0, VMW0);
        KTILE4(1, (void)0, (void)0, (void)0, (void)0, (void)0);
    }

    float* Cf = (float*)Cout;
    _Float16* Ch = (_Float16*)Cout;
#pragma unroll
    for (int mf = 0; mf < 8; mf++)
#pragma unroll
        for (int nf = 0; nf < 4; nf++)
#pragma unroll
            for (int r = 0; r < 4; r++) {
                size_t row = m0 + wr * 128 + mf * 16 + quad * 4 + r;
                size_t col = n0 + wc * 64 + nf * 16 + lcol;
                if (F16OUT)
                    Ch[row * N + col] = (_Float16)acc[mf][nf][r];
                else
                    Cf[row * N + col] = acc[mf][nf][r];
            }
#undef KTILE4
#undef STA
#undef STB
}

// ---------------------------------------------------------------------------
// 128x128 2-barrier MFMA GEMM (for Wo: full-chip grid, 3 blocks/CU)
// ---------------------------------------------------------------------------
template <bool F16OUT>
__global__ __launch_bounds__(256) void gemm_h(const _Float16* __restrict__ A,
                                              const _Float16* __restrict__ W,
                                              void* __restrict__ Cout,
                                              int M, int N, int K) {
    __shared__ __align__(16) _Float16 As[128 * 32];
    __shared__ __align__(16) _Float16 Bs[128 * 32];

    const int tid = threadIdx.x;
    const int wv = tid >> 6;
    const int ln = tid & 63;
    const int quad = ln >> 4;
    const int lcol = ln & 15;
    const int m0 = blockIdx.y * 128;
    const int n0 = blockIdx.x * 128;
    const int wm = (wv >> 1) * 64;
    const int wn = (wv & 1) * 64;

    const int srow = ln >> 2;
    const int kblk = (ln & 3) * 8;

    f32x4 acc[4][4];
#pragma unroll
    for (int i = 0; i < 4; i++)
#pragma unroll
        for (int j = 0; j < 4; j++) acc[i][j] = (f32x4){0.f, 0.f, 0.f, 0.f};

    for (int k0 = 0; k0 < K; k0 += 32) {
        __syncthreads();
#pragma unroll
        for (int j = 0; j < 2; j++) {
            int r = wv * 32 + j * 16 + srow;
            gl_lds16(A + (size_t)(m0 + r) * K + k0 + kblk, &As[r * 32 + kblk]);
            gl_lds16(W + (size_t)(n0 + r) * K + k0 + kblk, &Bs[r * 32 + kblk]);
        }
        __syncthreads();

        half8 af[4], bf[4];
#pragma unroll
        for (int ms = 0; ms < 4; ms++)
            af[ms] = *(const half8*)&As[(wm + ms * 16 + lcol) * 32 + quad * 8];
#pragma unroll
        for (int ns = 0; ns < 4; ns++)
            bf[ns] = *(const half8*)&Bs[(wn + ns * 16 + lcol) * 32 + quad * 8];
#pragma unroll
        for (int ms = 0; ms < 4; ms++)
#pragma unroll
            for (int ns = 0; ns < 4; ns++)
                acc[ms][ns] = __builtin_amdgcn_mfma_f32_16x16x32_f16(
                    af[ms], bf[ns], acc[ms][ns], 0, 0, 0);
    }

    float* Cf = (float*)Cout;
    _Float16* Ch = (_Float16*)Cout;
#pragma unroll
    for (int ms = 0; ms < 4; ms++)
#pragma unroll
        for (int ns = 0; ns < 4; ns++)
#pragma unroll
            for (int r = 0; r < 4; r++) {
                size_t row = m0 + wm + ms * 16 + quad * 4 + r;
                size_t col = n0 + wn + ns * 16 + lcol;
                if (F16OUT)
                    Ch[row * N + col] = (_Float16)acc[ms][ns][r];
                else
                    Cf[row * N + col] = acc[ms][ns][r];
            }
}

// ---------------------------------------------------------------------------
// Fused prep: RoPE (vectorized, uint4 pairs) + V transpose, one dispatch.
// blocks [0,4096): rope on Q,K of qkv; [4096,8192): V transpose -> vtb.
// rope thread: 8 consecutive d in chunk d8 and its pair chunk d8+64.
// ---------------------------------------------------------------------------
__global__ __launch_bounds__(256) void prep_kv(_Float16* __restrict__ qkv,
                                               _Float16* __restrict__ vtb) {
    __shared__ __align__(16) _Float16 T[32][72];
    int bx = blockIdx.x;
    const int tid = threadIdx.x;

    if (bx < 4096) {
        // ---- vectorized RoPE ----
        size_t idx = (size_t)bx * 256 + tid;   // over M*2*H*8 chunks
        int chunk = (int)(idx & 7);            // 0..7 -> d8 = chunk*8
        int h = (int)((idx >> 3) & (NHEADS - 1));
        int qk = (int)((idx >> 7) & 1);        // 0 = Q, 1 = K
        int m = (int)(idx >> 8);               // 0..4095
        int s = m & (SEQ - 1);
        float scale = qk ? 1.0f : 0.08838834764831845f;
        int d8 = chunk * 8;

        size_t base = (size_t)m * QKVLD + qk * DMODEL + h * HEADDIM + d8;
        union { uint4 u; _Float16 hh[8]; } u0, u1, o0, o1;
        u0.u = *(const uint4*)(qkv + base);
        u1.u = *(const uint4*)(qkv + base + 64);
#pragma unroll
        for (int j = 0; j < 8; j++) {
            float inv = __expf(-(float)(d8 + j) * 0.14391156831212787f);
            float f = (float)s * inv;
            float sn, cs;
            __sincosf(f, &sn, &cs);
            float x1 = (float)u0.hh[j];
            float x2 = (float)u1.hh[j];
            o0.hh[j] = (_Float16)((x1 * cs - x2 * sn) * scale);
            o1.hh[j] = (_Float16)((x2 * cs + x1 * sn) * scale);
        }
        *(uint4*)(qkv + base) = o0.u;
        *(uint4*)(qkv + base + 64) = o1.u;
    } else {
        // ---- V transpose ----
        int v = bx - 4096;
        const int s0 = (v & 31) * 64;
        const int d0 = ((v >> 5) & 3) * 32;
        const int bh = v >> 7;
        const int b = bh >> 4;
        const int h = bh & 15;

        {
            int s = tid >> 2;
            int d8 = (tid & 3) * 8;
            union { uint4 u; _Float16 hh[8]; } vv;
            vv.u = *(const uint4*)(qkv + (size_t)(b * SEQ + s0 + s) * QKVLD +
                                   2 * DMODEL + h * HEADDIM + d0 + d8);
#pragma unroll
            for (int j = 0; j < 8; j++) T[d8 + j][s] = vv.hh[j];
        }
        __syncthreads();

        int row = tid >> 3;
        int chunk = tid & 7;
        uint4 val = *(const uint4*)&T[row][chunk * 8];
        *(uint4*)(vtb + ((size_t)(bh * HEADDIM + d0 + row)) * SEQ + s0 + chunk * 8) = val;
    }
}

// ---------------------------------------------------------------------------
// Flash causal attention, f16 MFMA, swapped-QK^T in-register softmax.
// (proven round-3/5 structure: 16 q-rows/wave, sequential (qt, 15-qt) pair,
// every block does exactly 34 K-tile iterations, grid = 256 = 1/CU)
// ---------------------------------------------------------------------------
__global__ __launch_bounds__(512) void attn_mfma(const _Float16* __restrict__ qkv,
                                                 const _Float16* __restrict__ vtb,
                                                 _Float16* __restrict__ ab) {
    __shared__ __align__(16) _Float16 Ks[64][136];    // 17.4 KB
    __shared__ __align__(16) _Float16 Vts[128][72];   // 18.4 KB
    __shared__ __align__(16) _Float16 Ps[8][16][72];  // 18.4 KB (per-wave slices)

    const int tid = threadIdx.x;
    const int wave = tid >> 6;      // 0..7
    const int lane = tid & 63;
    const int quad = lane >> 4;
    const int lcol = lane & 15;

    const int h = blockIdx.y;
    const int b = blockIdx.z;
    const int qtA = blockIdx.x;     // 0..7 ; pair partner is 15-qtA

    const int kr0 = tid >> 4;             // 0..31 (second chunk: +32)
    const int ko0 = (tid & 15) * 8;       // 0..120
    const int vr0 = tid >> 3;             // 0..63 (second chunk: +64)
    const int vo0 = (tid & 7) * 8;        // 0..56

    const _Float16* kbp = qkv + (size_t)b * SEQ * QKVLD + DMODEL + h * HEADDIM;
    const _Float16* vbp = vtb + ((size_t)(b * NHEADS + h) * HEADDIM) * SEQ;

    uint4 kA, kB, vA, vB;  // named prefetch registers (avoid spill)
#define ISSUE_LOAD(kb)                                                        \
    do {                                                                      \
        int _kb = (kb);                                                       \
        kA = *(const uint4*)(kbp + (size_t)(_kb + kr0) * QKVLD + ko0);        \
        kB = *(const uint4*)(kbp + (size_t)(_kb + 32 + kr0) * QKVLD + ko0);   \
        vA = *(const uint4*)(vbp + (size_t)vr0 * SEQ + _kb + vo0);            \
        vB = *(const uint4*)(vbp + (size_t)(vr0 + 64) * SEQ + _kb + vo0);     \
    } while (0)

    ISSUE_LOAD(0);  // prologue prefetch for phase 0, kt 0

    for (int ph = 0; ph < 2; ++ph) {
        const int qt = ph ? (15 - qtA) : qtA;
        const int q0 = qt * 128 + wave * 16;   // this wave's 16 q-rows
        const int nkt = 2 * qt + 2;

        half8 aq[4];
        {
            const _Float16* qrow =
                qkv + (size_t)(b * SEQ + q0 + lcol) * QKVLD + h * HEADDIM;
#pragma unroll
            for (int st = 0; st < 4; st++)
                aq[st] = *(const half8*)(qrow + quad * 8 + 32 * st);
        }

        f32x4 Of[8];
#pragma unroll
        for (int dt = 0; dt < 8; dt++) Of[dt] = (f32x4){0.f, 0.f, 0.f, 0.f};
        float m_s = -1e30f, l_s = 0.f;   // running max/sum for q-row (q0+lcol)

        for (int kt = 0; kt < nkt; ++kt) {
            const int kbase = kt << 6;

            __syncthreads();  // all waves done reading previous tile's LDS
            *(uint4*)&Ks[kr0][ko0]        = kA;
            *(uint4*)&Ks[kr0 + 32][ko0]   = kB;
            *(uint4*)&Vts[vr0][vo0]       = vA;
            *(uint4*)&Vts[vr0 + 64][vo0]  = vB;
            __syncthreads();  // tile visible to all waves

            if (kt + 1 < nkt)      ISSUE_LOAD((kt + 1) << 6);
            else if (ph == 0)      ISSUE_LOAD(0);

            if (kbase > q0 + 15) continue;

            // Sc[s][r] = S[q = q0+lcol][k = kbase+16s+4*quad+r]
            f32x4 Sc[4];
#pragma unroll
            for (int s = 0; s < 4; s++) {
                Sc[s] = (f32x4){0.f, 0.f, 0.f, 0.f};
#pragma unroll
                for (int st = 0; st < 4; st++) {
                    half8 bk = *(const half8*)&Ks[16 * s + lcol][quad * 8 + 32 * st];
                    Sc[s] = __builtin_amdgcn_mfma_f32_16x16x32_f16(bk, aq[st], Sc[s],
                                                                   0, 0, 0);
                }
            }

            if (kbase + 63 > q0) {
#pragma unroll
                for (int s = 0; s < 4; s++)
#pragma unroll
                    for (int r = 0; r < 4; r++)
                        if (kbase + 16 * s + quad * 4 + r > q0 + lcol)
                            Sc[s][r] = -1e30f;
            }

            float pmax = Sc[0][0];
#pragma unroll
            for (int s = 0; s < 4; s++)
#pragma unroll
                for (int r = 0; r < 4; r++) pmax = fmaxf(pmax, Sc[s][r]);
            pmax = fmaxf(pmax, __shfl_xor(pmax, 16));
            pmax = fmaxf(pmax, __shfl_xor(pmax, 32));

            if (!__all(pmax <= m_s + 5.0f)) {
                float mnew = fmaxf(m_s, pmax);
                float alpha = __expf(m_s - mnew);
                m_s = mnew;
                l_s *= alpha;
                float a0 = __shfl(alpha, quad * 4 + 0);
                float a1 = __shfl(alpha, quad * 4 + 1);
                float a2 = __shfl(alpha, quad * 4 + 2);
                float a3 = __shfl(alpha, quad * 4 + 3);
#pragma unroll
                for (int dt = 0; dt < 8; dt++) {
                    Of[dt][0] *= a0;
                    Of[dt][1] *= a1;
                    Of[dt][2] *= a2;
                    Of[dt][3] *= a3;
                }
            }

            float sum = 0.f;
#pragma unroll
            for (int s = 0; s < 4; s++)
#pragma unroll
                for (int r = 0; r < 4; r++) {
                    float p = __expf(Sc[s][r] - m_s);
                    Sc[s][r] = p;
                    sum += p;
                }
            sum += __shfl_xor(sum, 16);
            sum += __shfl_xor(sum, 32);
            l_s += sum;

#pragma unroll
            for (int s = 0; s < 4; s++) {
                half4 pk;
                pk[0] = (_Float16)Sc[s][0]; pk[1] = (_Float16)Sc[s][1];
                pk[2] = (_Float16)Sc[s][2]; pk[3] = (_Float16)Sc[s][3];
                *(half4*)&Ps[wave][lcol][16 * s + 4 * quad] = pk;
            }

            half8 ap[2];
#pragma unroll
            for (int st = 0; st < 2; st++)
                ap[st] = *(const half8*)&Ps[wave][lcol][quad * 8 + 32 * st];
#pragma unroll
            for (int dt = 0; dt < 8; dt++) {
#pragma unroll
                for (int st = 0; st < 2; st++) {
                    half8 bv = *(const half8*)&Vts[16 * dt + lcol][quad * 8 + 32 * st];
                    Of[dt] = __builtin_amdgcn_mfma_f32_16x16x32_f16(ap[st], bv, Of[dt],
                                                                    0, 0, 0);
                }
            }
        }

        float invl = 1.f / l_s;
        float i0 = __shfl(invl, quad * 4 + 0);
        float i1 = __shfl(invl, quad * 4 + 1);
        float i2 = __shfl(invl, quad * 4 + 2);
        float i3 = __shfl(invl, quad * 4 + 3);
        _Float16* obase =
            ab + (size_t)(b * SEQ + q0 + quad * 4) * DMODEL + h * HEADDIM;
#pragma unroll
        for (int dt = 0; dt < 8; dt++) {
            obase[(size_t)0 * DMODEL + 16 * dt + lcol] = (_Float16)(Of[dt][0] * i0);
            obase[(size_t)1 * DMODEL + 16 * dt + lcol] = (_Float16)(Of[dt][1] * i1);
            obase[(size_t)2 * DMODEL + 16 * dt + lcol] = (_Float16)(Of[dt][2] * i2);
            obase[(size_t)3 * DMODEL + 16 * dt + lcol] = (_Float16)(Of[dt][3] * i3);
        }
    }
#undef ISSUE_LOAD
}

// ---------------------------------------------------------------------------
extern "C" void kernel_launch(void* const* d_in, const int* in_sizes, int n_in,
                              void* d_out, int out_size, void* d_ws, size_t ws_size,
                              hipStream_t stream) {
    const float* query = (const float*)d_in[0];
    const float* Wq = (const float*)d_in[1];
    const float* Wk = (const float*)d_in[2];
    const float* Wv = (const float*)d_in[3];
    const float* Wo = (const float*)d_in[4];
    float* out = (float*)d_out;

    const size_t MB = 1024 * 1024;
    char* w = (char*)d_ws;
    _Float16* xh   = (_Float16*)(w + 0 * MB);    // 16 MB f16 query (dead after QKV GEMM)
    _Float16* ab   = (_Float16*)(w + 0 * MB);    // 16 MB f16 attn out (reuses xh slot)
    _Float16* qkvh = (_Float16*)(w + 16 * MB);   // 48 MB f16 fused Q|K|V [M,6144]
    _Float16* Wh3  = (_Float16*)(w + 64 * MB);   // 24 MB f16 weight slot (QKV, then Wo)
    _Float16* vtb  = (_Float16*)(w + 88 * MB);   // 16 MB f16 V^T [B,H,128,S]

    const int convW = (DMODEL * DMODEL) / (256 * 8);   // 2048 blocks

    // all four input conversions in one dispatch (query + Wq/Wk/Wv)
    f2h_multi<<<4096 + 3 * 2048, 256, 0, stream>>>(query, Wq, Wk, Wv, xh, Wh3);

    // fused QKV projection: [4096, 6144] = xh [4096,2048] x Wh3[6144,2048]^T
    gemm8p<true><<<dim3(QKVLD / 256, MTOT / 256), 512, 0, stream>>>(
        xh, Wh3, qkvh, MTOT, QKVLD, DMODEL);

    // fused RoPE (vectorized) + V transpose
    prep_kv<<<4096 + 4096, 256, 0, stream>>>(qkvh, vtb);

    attn_mfma<<<dim3(8, NHEADS, BATCH), 512, 0, stream>>>(qkvh, vtb, ab);

    f2h_conv<<<convW, 256, 0, stream>>>(Wo, Wh3);
    // Wo: 128^2 tile -> (16,32) = 512 blocks, ~3/CU (full-chip, no half-grid tail)
    gemm_h<false><<<dim3(DMODEL / 128, MTOT / 128), 256, 0, stream>>>(
        ab, Wh3, out, MTOT, DMODEL, DMODEL);
}

// Round 11
// 406.071 us; speedup vs baseline: 1.0336x; 1.0336x over previous
//
#include <hip/hip_runtime.h>
#include <math.h>

// Problem constants
#define BATCH 2
#define SEQ 2048
#define DMODEL 2048
#define NHEADS 16
#define HEADDIM 128
#define MTOT (BATCH * SEQ)   // 4096
#define QKVLD 6144           // fused QKV row stride (Q|K|V)

typedef __attribute__((ext_vector_type(8))) _Float16 half8;  // 8 f16 (4 VGPRs)
typedef __attribute__((ext_vector_type(4))) _Float16 half4;  // 4 f16 (2 VGPRs)
typedef __attribute__((ext_vector_type(4))) float f32x4;     // 4 fp32

// async global -> LDS, 16B per lane (global_load_lds_dwordx4)
__device__ __forceinline__ void gl_lds16(const void* g, void* l) {
    __builtin_amdgcn_global_load_lds(
        (const __attribute__((address_space(1))) unsigned int*)g,
        (__attribute__((address_space(3))) unsigned int*)l, 16, 0, 0);
}

// ---------------------------------------------------------------------------
// fp32 -> f16 convert, 8 elems/thread; query + Wq/Wk/Wv (+ optionally Wo).
// blocks [0,4096): query->xh ; [4096,+3*2048): Wq/Wk/Wv->Wh3 ;
// [10240,+2048): Wo->woh (only launched when workspace fits).
// ---------------------------------------------------------------------------
__global__ __launch_bounds__(256) void f2h_multi(const float* __restrict__ query,
                                                 const float* __restrict__ Wq,
                                                 const float* __restrict__ Wk,
                                                 const float* __restrict__ Wv,
                                                 const float* __restrict__ Wo,
                                                 _Float16* __restrict__ xh,
                                                 _Float16* __restrict__ Wh3,
                                                 _Float16* __restrict__ woh) {
    const float* src;
    _Float16* dst;
    size_t i;
    int bx = blockIdx.x;
    if (bx < 4096) {
        src = query; dst = xh;
        i = ((size_t)bx * 256 + threadIdx.x) * 8;
    } else {
        int wi = bx - 4096;
        int y = wi >> 11;           // 0..3
        int off = wi & 2047;
        src = (y == 0) ? Wq : (y == 1) ? Wk : (y == 2) ? Wv : Wo;
        dst = (y == 3) ? woh : Wh3 + (size_t)y * (DMODEL * DMODEL);
        i = ((size_t)off * 256 + threadIdx.x) * 8;
    }
    float4 a = *(const float4*)(src + i);
    float4 b = *(const float4*)(src + i + 4);
    union { uint4 u; _Float16 h[8]; } o;
    o.h[0] = (_Float16)a.x; o.h[1] = (_Float16)a.y;
    o.h[2] = (_Float16)a.z; o.h[3] = (_Float16)a.w;
    o.h[4] = (_Float16)b.x; o.h[5] = (_Float16)b.y;
    o.h[6] = (_Float16)b.z; o.h[7] = (_Float16)b.w;
    *(uint4*)(dst + i) = o.u;
}

// plain single-source convert (fallback for Wo when workspace is tight)
__global__ __launch_bounds__(256) void f2h_conv(const float* __restrict__ src,
                                                _Float16* __restrict__ dst) {
    size_t i = ((size_t)blockIdx.x * 256 + threadIdx.x) * 8;
    float4 a = *(const float4*)(src + i);
    float4 b = *(const float4*)(src + i + 4);
    union { uint4 u; _Float16 h[8]; } o;
    o.h[0] = (_Float16)a.x; o.h[1] = (_Float16)a.y;
    o.h[2] = (_Float16)a.z; o.h[3] = (_Float16)a.w;
    o.h[4] = (_Float16)b.x; o.h[5] = (_Float16)b.y;
    o.h[6] = (_Float16)b.z; o.h[7] = (_Float16)b.w;
    *(uint4*)(dst + i) = o.u;
}

// ---------------------------------------------------------------------------
// 8-phase 256x256 MFMA GEMM (for the large QKV projection).
// BK=64, 8 waves (2Mx4N), double-buffered LDS, XOR-swizzled LDS reads,
// counted vmcnt(4) at phases 4/8, setprio around MFMA clusters.
// ---------------------------------------------------------------------------
#define SB0  __builtin_amdgcn_sched_barrier(0)
#define BAR  __builtin_amdgcn_s_barrier()
#define VMW4 do { SB0; asm volatile("s_waitcnt vmcnt(4)"); SB0; } while (0)
#define VMW0 do { SB0; asm volatile("s_waitcnt vmcnt(0)"); SB0; } while (0)

template <bool F16OUT>
__global__ __launch_bounds__(512, 2) void gemm8p(const _Float16* __restrict__ A,
                                                 const _Float16* __restrict__ W,
                                                 void* __restrict__ Cout,
                                                 int M, int N, int K) {
    __shared__ __align__(16) _Float16 LAb[2][2][128][64];  // 64 KB
    __shared__ __align__(16) _Float16 LBb[2][2][128][64];  // 64 KB

    const int tid = threadIdx.x;
    const int lane = tid & 63;
    const int wave = tid >> 6;
    const int quad = lane >> 4;
    const int lcol = lane & 15;
    const int wr = wave >> 2;    // 0..1  (M half)
    const int wc = wave & 3;     // 0..3  (N quarter)
    const int m0 = blockIdx.y * 256;
    const int n0 = blockIdx.x * 256;

    const int srow = tid >> 3;                // 0..63
    const int sc8p = tid & 7;                 // physical 16B chunk (linear LDS)
    const int sc8l = sc8p ^ (srow & 7);       // logical chunk (pre-swizzled src)

#define STA(BUF, HALF, KT)                                                     \
    do {                                                                       \
        _Pragma("unroll") for (int j = 0; j < 2; j++)                          \
            gl_lds16(A + (size_t)(m0 + (HALF)*128 + j*64 + srow) * K +         \
                         (KT)*64 + sc8l*8,                                     \
                     &LAb[BUF][HALF][j*64 + srow][sc8p*8]);                    \
    } while (0)
#define STB(BUF, HALF, KT)                                                     \
    do {                                                                       \
        _Pragma("unroll") for (int j = 0; j < 2; j++)                          \
            gl_lds16(W + (size_t)(n0 + (HALF)*128 + j*64 + srow) * K +         \
                         (KT)*64 + sc8l*8,                                     \
                     &LBb[BUF][HALF][j*64 + srow][sc8p*8]);                    \
    } while (0)

    auto rdA = [&](int buf, int mf, int ks) -> half8 {
        int R = mf * 16 + lcol;
        return *(const half8*)&LAb[buf][wr][R]
                [(ks * 32 + quad * 8) ^ ((lcol & 7) << 3)];
    };
    auto rdB = [&](int buf, int nf, int ks) -> half8 {
        int R = (wc & 1) * 64 + nf * 16 + lcol;
        return *(const half8*)&LBb[buf][wc >> 1][R]
                [(ks * 32 + quad * 8) ^ ((lcol & 7) << 3)];
    };

    f32x4 acc[8][4];
#pragma unroll
    for (int i = 0; i < 8; i++)
#pragma unroll
        for (int j = 0; j < 4; j++) acc[i][j] = (f32x4){0.f, 0.f, 0.f, 0.f};

#define KTILE4(BUF, S1, S2, S3, S4, W4)                                        \
    {                                                                          \
        half8 a[4][2], b[4][2];                                                \
        _Pragma("unroll") for (int mf = 0; mf < 4; mf++)                       \
            _Pragma("unroll") for (int ks = 0; ks < 2; ks++)                   \
                a[mf][ks] = rdA(BUF, mf, ks);                                  \
        _Pragma("unroll") for (int nf = 0; nf < 2; nf++)                       \
            _Pragma("unroll") for (int ks = 0; ks < 2; ks++)                   \
                b[nf][ks] = rdB(BUF, nf, ks);                                  \
        S1; SB0; BAR; SB0;                                                     \
        __builtin_amdgcn_s_setprio(1);                                         \
        _Pragma("unroll") for (int ks = 0; ks < 2; ks++)                       \
            _Pragma("unroll") for (int mf = 0; mf < 4; mf++)                   \
                _Pragma("unroll") for (int nf = 0; nf < 2; nf++)               \
                    acc[mf][nf] = __builtin_amdgcn_mfma_f32_16x16x32_f16(      \
                        a[mf][ks], b[nf][ks], acc[mf][nf], 0, 0, 0);           \
        __builtin_amdgcn_s_setprio(0); SB0; BAR; SB0;                          \
        _Pragma("unroll") for (int nf = 0; nf < 2; nf++)                       \
            _Pragma("unroll") for (int ks = 0; ks < 2; ks++)                   \
                b[2 + nf][ks] = rdB(BUF, 2 + nf, ks);                          \
        S2; SB0; BAR; SB0;                                                     \
        __builtin_amdgcn_s_setprio(1);                                         \
        _Pragma("unroll") for (int ks = 0; ks < 2; ks++)                       \
            _Pragma("unroll") for (int mf = 0; mf < 4; mf++)                   \
                _Pragma("unroll") for (int nf = 0; nf < 2; nf++)               \
                    acc[mf][2 + nf] = __builtin_amdgcn_mfma_f32_16x16x32_f16(  \
                        a[mf][ks], b[2 + nf][ks], acc[mf][2 + nf], 0, 0, 0);   \
        __builtin_amdgcn_s_setprio(0); SB0; BAR; SB0;                          \
        _Pragma("unroll") for (int mf = 0; mf < 4; mf++)                       \
            _Pragma("unroll") for (int ks = 0; ks < 2; ks++)                   \
                a[mf][ks] = rdA(BUF, 4 + mf, ks);                              \
        S3; SB0; BAR; SB0;                                                     \
        __builtin_amdgcn_s_setprio(1);                                         \
        _Pragma("unroll") for (int ks = 0; ks < 2; ks++)                       \
            _Pragma("unroll") for (int mf = 0; mf < 4; mf++)                   \
                _Pragma("unroll") for (int nf = 0; nf < 2; nf++)               \
                    acc[4 + mf][nf] = __builtin_amdgcn_mfma_f32_16x16x32_f16(  \
                        a[mf][ks], b[nf][ks], acc[4 + mf][nf], 0, 0, 0);       \
        __builtin_amdgcn_s_setprio(0); SB0; BAR; SB0;                          \
        S4; W4; BAR; SB0;                                                      \
        __builtin_amdgcn_s_setprio(1);                                         \
        _Pragma("unroll") for (int ks = 0; ks < 2; ks++)                       \
            _Pragma("unroll") for (int mf = 0; mf < 4; mf++)                   \
                _Pragma("unroll") for (int nf = 0; nf < 2; nf++)               \
                    acc[4 + mf][2 + nf] =                                      \
                        __builtin_amdgcn_mfma_f32_16x16x32_f16(                \
                            a[mf][ks], b[2 + nf][ks], acc[4 + mf][2 + nf],     \
                            0, 0, 0);                                          \
        __builtin_amdgcn_s_setprio(0); SB0; BAR; SB0;                          \
    }

    STB(0, 0, 0); STB(0, 1, 0); STA(0, 0, 0); STA(0, 1, 0);
    STB(1, 0, 1); STB(1, 1, 1);
    VMW4; BAR; SB0;

    const int niter = K >> 7;  // K/128 (2 K-tiles per iteration)
    for (int i = 0; i < niter - 1; ++i) {
        const int t0 = 2 * i;
        KTILE4(0, STA(1, 0, t0 + 1), STA(1, 1, t0 + 1),
                  STB(0, 0, t0 + 2), STB(0, 1, t0 + 2), VMW4);
        KTILE4(1, STA(0, 0, t0 + 2), STA(0, 1, t0 + 2),
                  STB(1, 0, t0 + 3), STB(1, 1, t0 + 3), VMW4);
    }
    {
        const int t0 = 2 * (niter - 1);
        KTILE4(0, STA(1, 0, t0 + 1), STA(1, 1, t0 + 1),
                  (void)0, (void)0, VMW0);
        KTILE4(1, (void)0, (void)0, (void)0, (void)0, (void)0);
    }

    float* Cf = (float*)Cout;
    _Float16* Ch = (_Float16*)Cout;
#pragma unroll
    for (int mf = 0; mf < 8; mf++)
#pragma unroll
        for (int nf = 0; nf < 4; nf++)
#pragma unroll
            for (int r = 0; r < 4; r++) {
                size_t row = m0 + wr * 128 + mf * 16 + quad * 4 + r;
                size_t col = n0 + wc * 64 + nf * 16 + lcol;
                if (F16OUT)
                    Ch[row * N + col] = (_Float16)acc[mf][nf][r];
                else
                    Cf[row * N + col] = acc[mf][nf][r];
            }
#undef KTILE4
#undef STA
#undef STB
}

// ---------------------------------------------------------------------------
// 128x128 2-barrier MFMA GEMM (for Wo: full-chip grid, 3 blocks/CU)
// ---------------------------------------------------------------------------
template <bool F16OUT>
__global__ __launch_bounds__(256) void gemm_h(const _Float16* __restrict__ A,
                                              const _Float16* __restrict__ W,
                                              void* __restrict__ Cout,
                                              int M, int N, int K) {
    __shared__ __align__(16) _Float16 As[128 * 32];
    __shared__ __align__(16) _Float16 Bs[128 * 32];

    const int tid = threadIdx.x;
    const int wv = tid >> 6;
    const int ln = tid & 63;
    const int quad = ln >> 4;
    const int lcol = ln & 15;
    const int m0 = blockIdx.y * 128;
    const int n0 = blockIdx.x * 128;
    const int wm = (wv >> 1) * 64;
    const int wn = (wv & 1) * 64;

    const int srow = ln >> 2;
    const int kblk = (ln & 3) * 8;

    f32x4 acc[4][4];
#pragma unroll
    for (int i = 0; i < 4; i++)
#pragma unroll
        for (int j = 0; j < 4; j++) acc[i][j] = (f32x4){0.f, 0.f, 0.f, 0.f};

    for (int k0 = 0; k0 < K; k0 += 32) {
        __syncthreads();
#pragma unroll
        for (int j = 0; j < 2; j++) {
            int r = wv * 32 + j * 16 + srow;
            gl_lds16(A + (size_t)(m0 + r) * K + k0 + kblk, &As[r * 32 + kblk]);
            gl_lds16(W + (size_t)(n0 + r) * K + k0 + kblk, &Bs[r * 32 + kblk]);
        }
        __syncthreads();

        half8 af[4], bf[4];
#pragma unroll
        for (int ms = 0; ms < 4; ms++)
            af[ms] = *(const half8*)&As[(wm + ms * 16 + lcol) * 32 + quad * 8];
#pragma unroll
        for (int ns = 0; ns < 4; ns++)
            bf[ns] = *(const half8*)&Bs[(wn + ns * 16 + lcol) * 32 + quad * 8];
#pragma unroll
        for (int ms = 0; ms < 4; ms++)
#pragma unroll
            for (int ns = 0; ns < 4; ns++)
                acc[ms][ns] = __builtin_amdgcn_mfma_f32_16x16x32_f16(
                    af[ms], bf[ns], acc[ms][ns], 0, 0, 0);
    }

    float* Cf = (float*)Cout;
    _Float16* Ch = (_Float16*)Cout;
#pragma unroll
    for (int ms = 0; ms < 4; ms++)
#pragma unroll
        for (int ns = 0; ns < 4; ns++)
#pragma unroll
            for (int r = 0; r < 4; r++) {
                size_t row = m0 + wm + ms * 16 + quad * 4 + r;
                size_t col = n0 + wn + ns * 16 + lcol;
                if (F16OUT)
                    Ch[row * N + col] = (_Float16)acc[ms][ns][r];
                else
                    Cf[row * N + col] = acc[ms][ns][r];
            }
}

// ---------------------------------------------------------------------------
// Fused prep: RoPE (vectorized, uint4 pairs) + V transpose, one dispatch.
// blocks [0,4096): rope on Q,K of qkv; [4096,8192): V transpose -> vtb.
// ---------------------------------------------------------------------------
__global__ __launch_bounds__(256) void prep_kv(_Float16* __restrict__ qkv,
                                               _Float16* __restrict__ vtb) {
    __shared__ __align__(16) _Float16 T[32][72];
    int bx = blockIdx.x;
    const int tid = threadIdx.x;

    if (bx < 4096) {
        // ---- vectorized RoPE ----
        size_t idx = (size_t)bx * 256 + tid;   // over M*2*H*8 chunks
        int chunk = (int)(idx & 7);            // 0..7 -> d8 = chunk*8
        int h = (int)((idx >> 3) & (NHEADS - 1));
        int qk = (int)((idx >> 7) & 1);        // 0 = Q, 1 = K
        int m = (int)(idx >> 8);               // 0..4095
        int s = m & (SEQ - 1);
        float scale = qk ? 1.0f : 0.08838834764831845f;
        int d8 = chunk * 8;

        size_t base = (size_t)m * QKVLD + qk * DMODEL + h * HEADDIM + d8;
        union { uint4 u; _Float16 hh[8]; } u0, u1, o0, o1;
        u0.u = *(const uint4*)(qkv + base);
        u1.u = *(const uint4*)(qkv + base + 64);
#pragma unroll
        for (int j = 0; j < 8; j++) {
            float inv = __expf(-(float)(d8 + j) * 0.14391156831212787f);
            float f = (float)s * inv;
            float sn, cs;
            __sincosf(f, &sn, &cs);
            float x1 = (float)u0.hh[j];
            float x2 = (float)u1.hh[j];
            o0.hh[j] = (_Float16)((x1 * cs - x2 * sn) * scale);
            o1.hh[j] = (_Float16)((x2 * cs + x1 * sn) * scale);
        }
        *(uint4*)(qkv + base) = o0.u;
        *(uint4*)(qkv + base + 64) = o1.u;
    } else {
        // ---- V transpose ----
        int v = bx - 4096;
        const int s0 = (v & 31) * 64;
        const int d0 = ((v >> 5) & 3) * 32;
        const int bh = v >> 7;
        const int b = bh >> 4;
        const int h = bh & 15;

        {
            int s = tid >> 2;
            int d8 = (tid & 3) * 8;
            union { uint4 u; _Float16 hh[8]; } vv;
            vv.u = *(const uint4*)(qkv + (size_t)(b * SEQ + s0 + s) * QKVLD +
                                   2 * DMODEL + h * HEADDIM + d0 + d8);
#pragma unroll
            for (int j = 0; j < 8; j++) T[d8 + j][s] = vv.hh[j];
        }
        __syncthreads();

        int row = tid >> 3;
        int chunk = tid & 7;
        uint4 val = *(const uint4*)&T[row][chunk * 8];
        *(uint4*)(vtb + ((size_t)(bh * HEADDIM + d0 + row)) * SEQ + s0 + chunk * 8) = val;
    }
}

// ---------------------------------------------------------------------------
// Flash causal attention, f16 MFMA, swapped-QK^T in-register softmax.
// 32 q-rows per wave (two 16-q groups sharing each K/V LDS read).
// Waves 0-3 own the low tile (qtA), waves 4-7 the high tile (15-qtA);
// the (qt,15-qt) pair is covered in ONE k-loop of nkt = 2*(15-qtA)+2 iters.
// (R8-measured faster than the 16-q sequential-pair version: ~85 vs 93 us.)
// grid (8, H, B), 512 threads.
// ---------------------------------------------------------------------------
__global__ __launch_bounds__(512) void attn_mfma(const _Float16* __restrict__ qkv,
                                                 const _Float16* __restrict__ vtb,
                                                 _Float16* __restrict__ ab) {
    __shared__ __align__(16) _Float16 Ks[64][136];    // 17.4 KB
    __shared__ __align__(16) _Float16 Vts[128][72];   // 18.4 KB
    __shared__ __align__(16) _Float16 Ps[8][16][72];  // 18.4 KB (per-wave slices)

    const int tid = threadIdx.x;
    const int wave = tid >> 6;      // 0..7
    const int lane = tid & 63;
    const int quad = lane >> 4;
    const int lcol = lane & 15;

    const int h = blockIdx.y;
    const int b = blockIdx.z;
    const int qtA = blockIdx.x;     // 0..7 ; high tile is 15-qtA

    const int wtile = (wave < 4) ? qtA : (15 - qtA);
    const int q0w = wtile * 128 + (wave & 3) * 32;   // this wave's 32 q-rows
    const int nkt = 2 * (15 - qtA) + 2;              // block-uniform

    const int kr0 = tid >> 4;             // 0..31 (second chunk: +32)
    const int ko0 = (tid & 15) * 8;       // 0..120
    const int vr0 = tid >> 3;             // 0..63 (second chunk: +64)
    const int vo0 = (tid & 7) * 8;        // 0..56

    const _Float16* kbp = qkv + (size_t)b * SEQ * QKVLD + DMODEL + h * HEADDIM;
    const _Float16* vbp = vtb + ((size_t)(b * NHEADS + h) * HEADDIM) * SEQ;

    uint4 kA, kB, vA, vB;
#define ISSUE_LOAD(kb)                                                        \
    do {                                                                      \
        int _kb = (kb);                                                       \
        kA = *(const uint4*)(kbp + (size_t)(_kb + kr0) * QKVLD + ko0);        \
        kB = *(const uint4*)(kbp + (size_t)(_kb + 32 + kr0) * QKVLD + ko0);   \
        vA = *(const uint4*)(vbp + (size_t)vr0 * SEQ + _kb + vo0);            \
        vB = *(const uint4*)(vbp + (size_t)(vr0 + 64) * SEQ + _kb + vo0);     \
    } while (0)

    ISSUE_LOAD(0);

    // Q for both 16-q groups
    half8 aq0[4], aq1[4];
    {
        const _Float16* q0p = qkv + (size_t)(b * SEQ + q0w + lcol) * QKVLD + h * HEADDIM;
        const _Float16* q1p = q0p + (size_t)16 * QKVLD;
#pragma unroll
        for (int st = 0; st < 4; st++) {
            aq0[st] = *(const half8*)(q0p + quad * 8 + 32 * st);
            aq1[st] = *(const half8*)(q1p + quad * 8 + 32 * st);
        }
    }

    f32x4 Of0[8], Of1[8];
#pragma unroll
    for (int dt = 0; dt < 8; dt++) {
        Of0[dt] = (f32x4){0.f, 0.f, 0.f, 0.f};
        Of1[dt] = (f32x4){0.f, 0.f, 0.f, 0.f};
    }
    float m_s0 = -1e30f, l_s0 = 0.f;
    float m_s1 = -1e30f, l_s1 = 0.f;

    for (int kt = 0; kt < nkt; ++kt) {
        const int kbase = kt << 6;

        __syncthreads();  // all waves done reading previous tile's LDS
        *(uint4*)&Ks[kr0][ko0]        = kA;
        *(uint4*)&Ks[kr0 + 32][ko0]   = kB;
        *(uint4*)&Vts[vr0][vo0]       = vA;
        *(uint4*)&Vts[vr0 + 64][vo0]  = vB;
        __syncthreads();  // tile visible to all waves

        if (kt + 1 < nkt) ISSUE_LOAD((kt + 1) << 6);

        // whole 32-q wave-tile masked: skip (barriers already passed)
        if (kbase > q0w + 31) continue;

        // QK^T swapped: Sc{g}[s][r] = S[q = q0w+16g+lcol][k = kbase+16s+4quad+r]
        f32x4 Sc0[4], Sc1[4];
#pragma unroll
        for (int s = 0; s < 4; s++) {
            Sc0[s] = (f32x4){0.f, 0.f, 0.f, 0.f};
            Sc1[s] = (f32x4){0.f, 0.f, 0.f, 0.f};
#pragma unroll
            for (int st = 0; st < 4; st++) {
                half8 bk = *(const half8*)&Ks[16 * s + lcol][quad * 8 + 32 * st];
                Sc0[s] = __builtin_amdgcn_mfma_f32_16x16x32_f16(bk, aq0[st], Sc0[s], 0, 0, 0);
                Sc1[s] = __builtin_amdgcn_mfma_f32_16x16x32_f16(bk, aq1[st], Sc1[s], 0, 0, 0);
            }
        }

        if (kbase + 63 > q0w) {  // diagonal region: causal mask per group
#pragma unroll
            for (int s = 0; s < 4; s++)
#pragma unroll
                for (int r = 0; r < 4; r++) {
                    int kk = kbase + 16 * s + quad * 4 + r;
                    if (kk > q0w + lcol)      Sc0[s][r] = -1e30f;
                    if (kk > q0w + 16 + lcol) Sc1[s][r] = -1e30f;
                }
        }

        half8 ap0[2], ap1[2];

        // ---- group 0 softmax + P0 round-trip ----
        {
            float pmax = Sc0[0][0];
#pragma unroll
            for (int s = 0; s < 4; s++)
#pragma unroll
                for (int r = 0; r < 4; r++) pmax = fmaxf(pmax, Sc0[s][r]);
            pmax = fmaxf(pmax, __shfl_xor(pmax, 16));
            pmax = fmaxf(pmax, __shfl_xor(pmax, 32));
            if (!__all(pmax <= m_s0 + 5.0f)) {
                float mnew = fmaxf(m_s0, pmax);
                float alpha = __expf(m_s0 - mnew);
                m_s0 = mnew;
                l_s0 *= alpha;
                float a0 = __shfl(alpha, quad * 4 + 0);
                float a1 = __shfl(alpha, quad * 4 + 1);
                float a2 = __shfl(alpha, quad * 4 + 2);
                float a3 = __shfl(alpha, quad * 4 + 3);
#pragma unroll
                for (int dt = 0; dt < 8; dt++) {
                    Of0[dt][0] *= a0; Of0[dt][1] *= a1;
                    Of0[dt][2] *= a2; Of0[dt][3] *= a3;
                }
            }
            float sum = 0.f;
#pragma unroll
            for (int s = 0; s < 4; s++)
#pragma unroll
                for (int r = 0; r < 4; r++) {
                    float p = __expf(Sc0[s][r] - m_s0);
                    Sc0[s][r] = p;
                    sum += p;
                }
            sum += __shfl_xor(sum, 16);
            sum += __shfl_xor(sum, 32);
            l_s0 += sum;
#pragma unroll
            for (int s = 0; s < 4; s++) {
                half4 pk;
                pk[0] = (_Float16)Sc0[s][0]; pk[1] = (_Float16)Sc0[s][1];
                pk[2] = (_Float16)Sc0[s][2]; pk[3] = (_Float16)Sc0[s][3];
                *(half4*)&Ps[wave][lcol][16 * s + 4 * quad] = pk;
            }
            ap0[0] = *(const half8*)&Ps[wave][lcol][quad * 8];
            ap0[1] = *(const half8*)&Ps[wave][lcol][quad * 8 + 32];
        }

        // ---- group 1 softmax + P1 round-trip (reuses the same Ps slice;
        //      same-wave DS ops to aliasing addresses stay in order) ----
        {
            float pmax = Sc1[0][0];
#pragma unroll
            for (int s = 0; s < 4; s++)
#pragma unroll
                for (int r = 0; r < 4; r++) pmax = fmaxf(pmax, Sc1[s][r]);
            pmax = fmaxf(pmax, __shfl_xor(pmax, 16));
            pmax = fmaxf(pmax, __shfl_xor(pmax, 32));
            if (!__all(pmax <= m_s1 + 5.0f)) {
                float mnew = fmaxf(m_s1, pmax);
                float alpha = __expf(m_s1 - mnew);
                m_s1 = mnew;
                l_s1 *= alpha;
                float a0 = __shfl(alpha, quad * 4 + 0);
                float a1 = __shfl(alpha, quad * 4 + 1);
                float a2 = __shfl(alpha, quad * 4 + 2);
                float a3 = __shfl(alpha, quad * 4 + 3);
#pragma unroll
                for (int dt = 0; dt < 8; dt++) {
                    Of1[dt][0] *= a0; Of1[dt][1] *= a1;
                    Of1[dt][2] *= a2; Of1[dt][3] *= a3;
                }
            }
            float sum = 0.f;
#pragma unroll
            for (int s = 0; s < 4; s++)
#pragma unroll
                for (int r = 0; r < 4; r++) {
                    float p = __expf(Sc1[s][r] - m_s1);
                    Sc1[s][r] = p;
                    sum += p;
                }
            sum += __shfl_xor(sum, 16);
            sum += __shfl_xor(sum, 32);
            l_s1 += sum;
#pragma unroll
            for (int s = 0; s < 4; s++) {
                half4 pk;
                pk[0] = (_Float16)Sc1[s][0]; pk[1] = (_Float16)Sc1[s][1];
                pk[2] = (_Float16)Sc1[s][2]; pk[3] = (_Float16)Sc1[s][3];
                *(half4*)&Ps[wave][lcol][16 * s + 4 * quad] = pk;
            }
            ap1[0] = *(const half8*)&Ps[wave][lcol][quad * 8];
            ap1[1] = *(const half8*)&Ps[wave][lcol][quad * 8 + 32];
        }

        // PV: each bv read feeds BOTH groups (the LDS amortization win)
#pragma unroll
        for (int dt = 0; dt < 8; dt++) {
#pragma unroll
            for (int st = 0; st < 2; st++) {
                half8 bv = *(const half8*)&Vts[16 * dt + lcol][quad * 8 + 32 * st];
                Of0[dt] = __builtin_amdgcn_mfma_f32_16x16x32_f16(
                    st == 0 ? ap0[0] : ap0[1], bv, Of0[dt], 0, 0, 0);
                Of1[dt] = __builtin_amdgcn_mfma_f32_16x16x32_f16(
                    st == 0 ? ap1[0] : ap1[1], bv, Of1[dt], 0, 0, 0);
            }
        }
    }

    // epilogue, per group
    {
        float invl = 1.f / l_s0;
        float i0 = __shfl(invl, quad * 4 + 0);
        float i1 = __shfl(invl, quad * 4 + 1);
        float i2 = __shfl(invl, quad * 4 + 2);
        float i3 = __shfl(invl, quad * 4 + 3);
        _Float16* obase =
            ab + (size_t)(b * SEQ + q0w + quad * 4) * DMODEL + h * HEADDIM;
#pragma unroll
        for (int dt = 0; dt < 8; dt++) {
            obase[(size_t)0 * DMODEL + 16 * dt + lcol] = (_Float16)(Of0[dt][0] * i0);
            obase[(size_t)1 * DMODEL + 16 * dt + lcol] = (_Float16)(Of0[dt][1] * i1);
            obase[(size_t)2 * DMODEL + 16 * dt + lcol] = (_Float16)(Of0[dt][2] * i2);
            obase[(size_t)3 * DMODEL + 16 * dt + lcol] = (_Float16)(Of0[dt][3] * i3);
        }
    }
    {
        float invl = 1.f / l_s1;
        float i0 = __shfl(invl, quad * 4 + 0);
        float i1 = __shfl(invl, quad * 4 + 1);
        float i2 = __shfl(invl, quad * 4 + 2);
        float i3 = __shfl(invl, quad * 4 + 3);
        _Float16* obase =
            ab + (size_t)(b * SEQ + q0w + 16 + quad * 4) * DMODEL + h * HEADDIM;
#pragma unroll
        for (int dt = 0; dt < 8; dt++) {
            obase[(size_t)0 * DMODEL + 16 * dt + lcol] = (_Float16)(Of1[dt][0] * i0);
            obase[(size_t)1 * DMODEL + 16 * dt + lcol] = (_Float16)(Of1[dt][1] * i1);
            obase[(size_t)2 * DMODEL + 16 * dt + lcol] = (_Float16)(Of1[dt][2] * i2);
            obase[(size_t)3 * DMODEL + 16 * dt + lcol] = (_Float16)(Of1[dt][3] * i3);
        }
    }
#undef ISSUE_LOAD
}

// ---------------------------------------------------------------------------
extern "C" void kernel_launch(void* const* d_in, const int* in_sizes, int n_in,
                              void* d_out, int out_size, void* d_ws, size_t ws_size,
                              hipStream_t stream) {
    const float* query = (const float*)d_in[0];
    const float* Wq = (const float*)d_in[1];
    const float* Wk = (const float*)d_in[2];
    const float* Wv = (const float*)d_in[3];
    const float* Wo = (const float*)d_in[4];
    float* out = (float*)d_out;

    const size_t MB = 1024 * 1024;
    char* w = (char*)d_ws;
    _Float16* xh   = (_Float16*)(w + 0 * MB);    // 16 MB f16 query (dead after QKV GEMM)
    _Float16* ab   = (_Float16*)(w + 0 * MB);    // 16 MB f16 attn out (reuses xh slot)
    _Float16* qkvh = (_Float16*)(w + 16 * MB);   // 48 MB f16 fused Q|K|V [M,6144]
    _Float16* Wh3  = (_Float16*)(w + 64 * MB);   // 24 MB f16 weight slot (QKV)
    _Float16* vtb  = (_Float16*)(w + 88 * MB);   // 16 MB f16 V^T [B,H,128,S]
    _Float16* woh  = (_Float16*)(w + 104 * MB);  // 8 MB f16 Wo (only if ws fits)

    const int convW = (DMODEL * DMODEL) / (256 * 8);   // 2048 blocks
    const bool fuseWo = ws_size >= (size_t)112 * MB;

    // all input conversions in one dispatch (query + Wq/Wk/Wv [+ Wo])
    int convBlocks = 4096 + (fuseWo ? 4 : 3) * 2048;
    f2h_multi<<<convBlocks, 256, 0, stream>>>(query, Wq, Wk, Wv, Wo, xh, Wh3, woh);

    // fused QKV projection: [4096, 6144] = xh [4096,2048] x Wh3[6144,2048]^T
    gemm8p<true><<<dim3(QKVLD / 256, MTOT / 256), 512, 0, stream>>>(
        xh, Wh3, qkvh, MTOT, QKVLD, DMODEL);

    // fused RoPE (vectorized) + V transpose
    prep_kv<<<4096 + 4096, 256, 0, stream>>>(qkvh, vtb);

    attn_mfma<<<dim3(8, NHEADS, BATCH), 512, 0, stream>>>(qkvh, vtb, ab);

    const _Float16* woSrc;
    if (fuseWo) {
        woSrc = woh;          // converted in dispatch 1
    } else {
        f2h_conv<<<convW, 256, 0, stream>>>(Wo, Wh3);  // fallback: late convert
        woSrc = Wh3;
    }
    // Wo: 128^2 tile -> (16,32) = 512 blocks, ~3/CU (full-chip, no half-grid tail)
    gemm_h<false><<<dim3(DMODEL / 128, MTOT / 128), 256, 0, stream>>>(
        ab, woSrc, out, MTOT, DMODEL, DMODEL);
}

// Round 12
// 384.138 us; speedup vs baseline: 1.0926x; 1.0571x over previous
//
#include <hip/hip_runtime.h>
#include <math.h>

// Problem constants
#define BATCH 2
#define SEQ 2048
#define DMODEL 2048
#define NHEADS 16
#define HEADDIM 128
#define MTOT (BATCH * SEQ)   // 4096
#define QKVLD 6144           // fused QKV row stride (Q|K|V)

typedef __attribute__((ext_vector_type(8))) _Float16 half8;  // 8 f16 (4 VGPRs)
typedef __attribute__((ext_vector_type(4))) _Float16 half4;  // 4 f16 (2 VGPRs)
typedef __attribute__((ext_vector_type(4))) float f32x4;     // 4 fp32

// async global -> LDS, 16B per lane (global_load_lds_dwordx4)
__device__ __forceinline__ void gl_lds16(const void* g, void* l) {
    __builtin_amdgcn_global_load_lds(
        (const __attribute__((address_space(1))) unsigned int*)g,
        (__attribute__((address_space(3))) unsigned int*)l, 16, 0, 0);
}

// ---------------------------------------------------------------------------
// fp32 -> f16 convert, 8 elems/thread; query + Wq/Wk/Wv (+ optionally Wo).
// ---------------------------------------------------------------------------
__global__ __launch_bounds__(256) void f2h_multi(const float* __restrict__ query,
                                                 const float* __restrict__ Wq,
                                                 const float* __restrict__ Wk,
                                                 const float* __restrict__ Wv,
                                                 const float* __restrict__ Wo,
                                                 _Float16* __restrict__ xh,
                                                 _Float16* __restrict__ Wh3,
                                                 _Float16* __restrict__ woh) {
    const float* src;
    _Float16* dst;
    size_t i;
    int bx = blockIdx.x;
    if (bx < 4096) {
        src = query; dst = xh;
        i = ((size_t)bx * 256 + threadIdx.x) * 8;
    } else {
        int wi = bx - 4096;
        int y = wi >> 11;           // 0..3
        int off = wi & 2047;
        src = (y == 0) ? Wq : (y == 1) ? Wk : (y == 2) ? Wv : Wo;
        dst = (y == 3) ? woh : Wh3 + (size_t)y * (DMODEL * DMODEL);
        i = ((size_t)off * 256 + threadIdx.x) * 8;
    }
    float4 a = *(const float4*)(src + i);
    float4 b = *(const float4*)(src + i + 4);
    union { uint4 u; _Float16 h[8]; } o;
    o.h[0] = (_Float16)a.x; o.h[1] = (_Float16)a.y;
    o.h[2] = (_Float16)a.z; o.h[3] = (_Float16)a.w;
    o.h[4] = (_Float16)b.x; o.h[5] = (_Float16)b.y;
    o.h[6] = (_Float16)b.z; o.h[7] = (_Float16)b.w;
    *(uint4*)(dst + i) = o.u;
}

// plain single-source convert (fallback for Wo when workspace is tight)
__global__ __launch_bounds__(256) void f2h_conv(const float* __restrict__ src,
                                                _Float16* __restrict__ dst) {
    size_t i = ((size_t)blockIdx.x * 256 + threadIdx.x) * 8;
    float4 a = *(const float4*)(src + i);
    float4 b = *(const float4*)(src + i + 4);
    union { uint4 u; _Float16 h[8]; } o;
    o.h[0] = (_Float16)a.x; o.h[1] = (_Float16)a.y;
    o.h[2] = (_Float16)a.z; o.h[3] = (_Float16)a.w;
    o.h[4] = (_Float16)b.x; o.h[5] = (_Float16)b.y;
    o.h[6] = (_Float16)b.z; o.h[7] = (_Float16)b.w;
    *(uint4*)(dst + i) = o.u;
}

// ---------------------------------------------------------------------------
// 8-phase 256x256 MFMA GEMM with FUSED epilogue (QKV projection only):
//  - Q/K tiles (n0 < 4096): acc -> LDS (K-loop buffers are dead; aliased) ->
//    rope (scale folded for Q) -> coalesced f16 stores to qkv.
//  - V tiles (n0 >= 4096): acc stored DIRECTLY transposed to vtb [B,H,128,S]
//    (half4 = 4 consecutive s per store). No rope, no LDS.
// Replaces the separate prep_kv dispatch (rope + V-transpose round-trip).
// ---------------------------------------------------------------------------
#define SB0  __builtin_amdgcn_sched_barrier(0)
#define BAR  __builtin_amdgcn_s_barrier()
#define VMW4 do { SB0; asm volatile("s_waitcnt vmcnt(4)"); SB0; } while (0)
#define VMW0 do { SB0; asm volatile("s_waitcnt vmcnt(0)"); SB0; } while (0)

__global__ __launch_bounds__(512, 2) void gemm_qkv(const _Float16* __restrict__ A,
                                                   const _Float16* __restrict__ W,
                                                   _Float16* __restrict__ qkv,
                                                   _Float16* __restrict__ vtb) {
    // one raw LDS pool: K-loop double buffers alias the epilogue exchange tile
    __shared__ __align__(16) char lds_raw[131072];
    _Float16 (*LAb)[2][128][64] = (_Float16(*)[2][128][64])lds_raw;           // [2][2][128][64]
    _Float16 (*LBb)[2][128][64] = (_Float16(*)[2][128][64])(lds_raw + 65536); // [2][2][128][64]

    const int K = DMODEL;
    const int tid = threadIdx.x;
    const int lane = tid & 63;
    const int wave = tid >> 6;
    const int quad = lane >> 4;
    const int lcol = lane & 15;
    const int wr = wave >> 2;    // 0..1  (M half)
    const int wc = wave & 3;     // 0..3  (N quarter)
    const int m0 = blockIdx.y * 256;
    const int n0 = blockIdx.x * 256;

    const int srow = tid >> 3;                // 0..63
    const int sc8p = tid & 7;                 // physical 16B chunk (linear LDS)
    const int sc8l = sc8p ^ (srow & 7);       // logical chunk (pre-swizzled src)

#define STA(BUF, HALF, KT)                                                     \
    do {                                                                       \
        _Pragma("unroll") for (int j = 0; j < 2; j++)                          \
            gl_lds16(A + (size_t)(m0 + (HALF)*128 + j*64 + srow) * K +         \
                         (KT)*64 + sc8l*8,                                     \
                     &LAb[BUF][HALF][j*64 + srow][sc8p*8]);                    \
    } while (0)
#define STB(BUF, HALF, KT)                                                     \
    do {                                                                       \
        _Pragma("unroll") for (int j = 0; j < 2; j++)                          \
            gl_lds16(W + (size_t)(n0 + (HALF)*128 + j*64 + srow) * K +         \
                         (KT)*64 + sc8l*8,                                     \
                     &LBb[BUF][HALF][j*64 + srow][sc8p*8]);                    \
    } while (0)

    auto rdA = [&](int buf, int mf, int ks) -> half8 {
        int R = mf * 16 + lcol;
        return *(const half8*)&LAb[buf][wr][R]
                [(ks * 32 + quad * 8) ^ ((lcol & 7) << 3)];
    };
    auto rdB = [&](int buf, int nf, int ks) -> half8 {
        int R = (wc & 1) * 64 + nf * 16 + lcol;
        return *(const half8*)&LBb[buf][wc >> 1][R]
                [(ks * 32 + quad * 8) ^ ((lcol & 7) << 3)];
    };

    f32x4 acc[8][4];
#pragma unroll
    for (int i = 0; i < 8; i++)
#pragma unroll
        for (int j = 0; j < 4; j++) acc[i][j] = (f32x4){0.f, 0.f, 0.f, 0.f};

#define KTILE4(BUF, S1, S2, S3, S4, W4)                                        \
    {                                                                          \
        half8 a[4][2], b[4][2];                                                \
        _Pragma("unroll") for (int mf = 0; mf < 4; mf++)                       \
            _Pragma("unroll") for (int ks = 0; ks < 2; ks++)                   \
                a[mf][ks] = rdA(BUF, mf, ks);                                  \
        _Pragma("unroll") for (int nf = 0; nf < 2; nf++)                       \
            _Pragma("unroll") for (int ks = 0; ks < 2; ks++)                   \
                b[nf][ks] = rdB(BUF, nf, ks);                                  \
        S1; SB0; BAR; SB0;                                                     \
        __builtin_amdgcn_s_setprio(1);                                         \
        _Pragma("unroll") for (int ks = 0; ks < 2; ks++)                       \
            _Pragma("unroll") for (int mf = 0; mf < 4; mf++)                   \
                _Pragma("unroll") for (int nf = 0; nf < 2; nf++)               \
                    acc[mf][nf] = __builtin_amdgcn_mfma_f32_16x16x32_f16(      \
                        a[mf][ks], b[nf][ks], acc[mf][nf], 0, 0, 0);           \
        __builtin_amdgcn_s_setprio(0); SB0; BAR; SB0;                          \
        _Pragma("unroll") for (int nf = 0; nf < 2; nf++)                       \
            _Pragma("unroll") for (int ks = 0; ks < 2; ks++)                   \
                b[2 + nf][ks] = rdB(BUF, 2 + nf, ks);                          \
        S2; SB0; BAR; SB0;                                                     \
        __builtin_amdgcn_s_setprio(1);                                         \
        _Pragma("unroll") for (int ks = 0; ks < 2; ks++)                       \
            _Pragma("unroll") for (int mf = 0; mf < 4; mf++)                   \
                _Pragma("unroll") for (int nf = 0; nf < 2; nf++)               \
                    acc[mf][2 + nf] = __builtin_amdgcn_mfma_f32_16x16x32_f16(  \
                        a[mf][ks], b[2 + nf][ks], acc[mf][2 + nf], 0, 0, 0);   \
        __builtin_amdgcn_s_setprio(0); SB0; BAR; SB0;                          \
        _Pragma("unroll") for (int mf = 0; mf < 4; mf++)                       \
            _Pragma("unroll") for (int ks = 0; ks < 2; ks++)                   \
                a[mf][ks] = rdA(BUF, 4 + mf, ks);                              \
        S3; SB0; BAR; SB0;                                                     \
        __builtin_amdgcn_s_setprio(1);                                         \
        _Pragma("unroll") for (int ks = 0; ks < 2; ks++)                       \
            _Pragma("unroll") for (int mf = 0; mf < 4; mf++)                   \
                _Pragma("unroll") for (int nf = 0; nf < 2; nf++)               \
                    acc[4 + mf][nf] = __builtin_amdgcn_mfma_f32_16x16x32_f16(  \
                        a[mf][ks], b[nf][ks], acc[4 + mf][nf], 0, 0, 0);       \
        __builtin_amdgcn_s_setprio(0); SB0; BAR; SB0;                          \
        S4; W4; BAR; SB0;                                                      \
        __builtin_amdgcn_s_setprio(1);                                         \
        _Pragma("unroll") for (int ks = 0; ks < 2; ks++)                       \
            _Pragma("unroll") for (int mf = 0; mf < 4; mf++)                   \
                _Pragma("unroll") for (int nf = 0; nf < 2; nf++)               \
                    acc[4 + mf][2 + nf] =                                      \
                        __builtin_amdgcn_mfma_f32_16x16x32_f16(                \
                            a[mf][ks], b[2 + nf][ks], acc[4 + mf][2 + nf],     \
                            0, 0, 0);                                          \
        __builtin_amdgcn_s_setprio(0); SB0; BAR; SB0;                          \
    }

    STB(0, 0, 0); STB(0, 1, 0); STA(0, 0, 0); STA(0, 1, 0);
    STB(1, 0, 1); STB(1, 1, 1);
    VMW4; BAR; SB0;

    const int niter = K >> 7;  // K/128 (2 K-tiles per iteration)
    for (int i = 0; i < niter - 1; ++i) {
        const int t0 = 2 * i;
        KTILE4(0, STA(1, 0, t0 + 1), STA(1, 1, t0 + 1),
                  STB(0, 0, t0 + 2), STB(0, 1, t0 + 2), VMW4);
        KTILE4(1, STA(0, 0, t0 + 2), STA(0, 1, t0 + 2),
                  STB(1, 0, t0 + 3), STB(1, 1, t0 + 3), VMW4);
    }
    {
        const int t0 = 2 * (niter - 1);
        KTILE4(0, STA(1, 0, t0 + 1), STA(1, 1, t0 + 1),
                  (void)0, (void)0, VMW0);
        KTILE4(1, (void)0, (void)0, (void)0, (void)0, (void)0);
    }

    // ---------------- fused epilogue ----------------
    if (n0 < 2 * DMODEL) {
        // Q or K tile: rope via LDS exchange (pairs (d, d+64) live in
        // different waves' accumulators). K-loop LDS is dead; alias it.
        const float scale = (n0 < DMODEL) ? 0.08838834764831845f : 1.0f;
        _Float16 (*T)[256] = (_Float16(*)[256])lds_raw;

        __syncthreads();  // all waves past their last LDS read of the K-loop
#pragma unroll
        for (int mf = 0; mf < 8; mf++)
#pragma unroll
            for (int nf = 0; nf < 4; nf++)
#pragma unroll
                for (int r = 0; r < 4; r++)
                    T[wr * 128 + mf * 16 + quad * 4 + r]
                     [wc * 64 + nf * 16 + lcol] = (_Float16)acc[mf][nf][r];
        __syncthreads();

        // 4096 (row, head-half, chunk) units; 8 per thread.
#pragma unroll
        for (int u = 0; u < 8; ++u) {
            int unit = tid + 512 * u;
            int row = unit >> 4;              // 0..255
            int hh = (unit >> 3) & 1;         // which head in this tile
            int c8 = (unit & 7) * 8;          // first-half d chunk
            int s = (m0 + row) & (SEQ - 1);
            int cb = hh * 128 + c8;
            half8 x1v = *(const half8*)&T[row][cb];
            half8 x2v = *(const half8*)&T[row][cb + 64];
            half8 o1v, o2v;
#pragma unroll
            for (int j = 0; j < 8; j++) {
                float inv = __expf(-(float)(c8 + j) * 0.14391156831212787f);
                float f = (float)s * inv;
                float sn, cs;
                __sincosf(f, &sn, &cs);
                float x1 = (float)x1v[j];
                float x2 = (float)x2v[j];
                o1v[j] = (_Float16)((x1 * cs - x2 * sn) * scale);
                o2v[j] = (_Float16)((x2 * cs + x1 * sn) * scale);
            }
            _Float16* g = qkv + (size_t)(m0 + row) * QKVLD + n0 + cb;
            *(half8*)g = o1v;
            *(half8*)(g + 64) = o2v;
        }
    } else {
        // V tile: direct transposed store to vtb [B,H,128,S]
        const int vbase = n0 - 2 * DMODEL;
#pragma unroll
        for (int mf = 0; mf < 8; mf++) {
            int m = m0 + wr * 128 + mf * 16 + quad * 4;
            int b = m >> 11;
            int s = m & (SEQ - 1);
#pragma unroll
            for (int nf = 0; nf < 4; nf++) {
                int col = vbase + wc * 64 + nf * 16 + lcol;
                int hh = col >> 7;
                int d = col & 127;
                half4 pk;
                pk[0] = (_Float16)acc[mf][nf][0];
                pk[1] = (_Float16)acc[mf][nf][1];
                pk[2] = (_Float16)acc[mf][nf][2];
                pk[3] = (_Float16)acc[mf][nf][3];
                *(half4*)(vtb +
                          ((size_t)((b * NHEADS + hh) * HEADDIM + d)) * SEQ + s) = pk;
            }
        }
    }
#undef KTILE4
#undef STA
#undef STB
}

// ---------------------------------------------------------------------------
// 128x128 2-barrier MFMA GEMM (for Wo: full-chip grid, 3 blocks/CU)
// ---------------------------------------------------------------------------
template <bool F16OUT>
__global__ __launch_bounds__(256) void gemm_h(const _Float16* __restrict__ A,
                                              const _Float16* __restrict__ W,
                                              void* __restrict__ Cout,
                                              int M, int N, int K) {
    __shared__ __align__(16) _Float16 As[128 * 32];
    __shared__ __align__(16) _Float16 Bs[128 * 32];

    const int tid = threadIdx.x;
    const int wv = tid >> 6;
    const int ln = tid & 63;
    const int quad = ln >> 4;
    const int lcol = ln & 15;
    const int m0 = blockIdx.y * 128;
    const int n0 = blockIdx.x * 128;
    const int wm = (wv >> 1) * 64;
    const int wn = (wv & 1) * 64;

    const int srow = ln >> 2;
    const int kblk = (ln & 3) * 8;

    f32x4 acc[4][4];
#pragma unroll
    for (int i = 0; i < 4; i++)
#pragma unroll
        for (int j = 0; j < 4; j++) acc[i][j] = (f32x4){0.f, 0.f, 0.f, 0.f};

    for (int k0 = 0; k0 < K; k0 += 32) {
        __syncthreads();
#pragma unroll
        for (int j = 0; j < 2; j++) {
            int r = wv * 32 + j * 16 + srow;
            gl_lds16(A + (size_t)(m0 + r) * K + k0 + kblk, &As[r * 32 + kblk]);
            gl_lds16(W + (size_t)(n0 + r) * K + k0 + kblk, &Bs[r * 32 + kblk]);
        }
        __syncthreads();

        half8 af[4], bf[4];
#pragma unroll
        for (int ms = 0; ms < 4; ms++)
            af[ms] = *(const half8*)&As[(wm + ms * 16 + lcol) * 32 + quad * 8];
#pragma unroll
        for (int ns = 0; ns < 4; ns++)
            bf[ns] = *(const half8*)&Bs[(wn + ns * 16 + lcol) * 32 + quad * 8];
#pragma unroll
        for (int ms = 0; ms < 4; ms++)
#pragma unroll
            for (int ns = 0; ns < 4; ns++)
                acc[ms][ns] = __builtin_amdgcn_mfma_f32_16x16x32_f16(
                    af[ms], bf[ns], acc[ms][ns], 0, 0, 0);
    }

    float* Cf = (float*)Cout;
    _Float16* Ch = (_Float16*)Cout;
#pragma unroll
    for (int ms = 0; ms < 4; ms++)
#pragma unroll
        for (int ns = 0; ns < 4; ns++)
#pragma unroll
            for (int r = 0; r < 4; r++) {
                size_t row = m0 + wm + ms * 16 + quad * 4 + r;
                size_t col = n0 + wn + ns * 16 + lcol;
                if (F16OUT)
                    Ch[row * N + col] = (_Float16)acc[ms][ns][r];
                else
                    Cf[row * N + col] = acc[ms][ns][r];
            }
}

// ---------------------------------------------------------------------------
// Flash causal attention, f16 MFMA, swapped-QK^T in-register softmax.
// 32 q-rows per wave (two 16-q groups sharing each K/V LDS read).
// grid (8, H, B), 512 threads.
// ---------------------------------------------------------------------------
__global__ __launch_bounds__(512) void attn_mfma(const _Float16* __restrict__ qkv,
                                                 const _Float16* __restrict__ vtb,
                                                 _Float16* __restrict__ ab) {
    __shared__ __align__(16) _Float16 Ks[64][136];    // 17.4 KB
    __shared__ __align__(16) _Float16 Vts[128][72];   // 18.4 KB
    __shared__ __align__(16) _Float16 Ps[8][16][72];  // 18.4 KB (per-wave slices)

    const int tid = threadIdx.x;
    const int wave = tid >> 6;      // 0..7
    const int lane = tid & 63;
    const int quad = lane >> 4;
    const int lcol = lane & 15;

    const int h = blockIdx.y;
    const int b = blockIdx.z;
    const int qtA = blockIdx.x;     // 0..7 ; high tile is 15-qtA

    const int wtile = (wave < 4) ? qtA : (15 - qtA);
    const int q0w = wtile * 128 + (wave & 3) * 32;   // this wave's 32 q-rows
    const int nkt = 2 * (15 - qtA) + 2;              // block-uniform

    const int kr0 = tid >> 4;             // 0..31 (second chunk: +32)
    const int ko0 = (tid & 15) * 8;       // 0..120
    const int vr0 = tid >> 3;             // 0..63 (second chunk: +64)
    const int vo0 = (tid & 7) * 8;        // 0..56

    const _Float16* kbp = qkv + (size_t)b * SEQ * QKVLD + DMODEL + h * HEADDIM;
    const _Float16* vbp = vtb + ((size_t)(b * NHEADS + h) * HEADDIM) * SEQ;

    uint4 kA, kB, vA, vB;
#define ISSUE_LOAD(kb)                                                        \
    do {                                                                      \
        int _kb = (kb);                                                       \
        kA = *(const uint4*)(kbp + (size_t)(_kb + kr0) * QKVLD + ko0);        \
        kB = *(const uint4*)(kbp + (size_t)(_kb + 32 + kr0) * QKVLD + ko0);   \
        vA = *(const uint4*)(vbp + (size_t)vr0 * SEQ + _kb + vo0);            \
        vB = *(const uint4*)(vbp + (size_t)(vr0 + 64) * SEQ + _kb + vo0);     \
    } while (0)

    ISSUE_LOAD(0);

    // Q for both 16-q groups
    half8 aq0[4], aq1[4];
    {
        const _Float16* q0p = qkv + (size_t)(b * SEQ + q0w + lcol) * QKVLD + h * HEADDIM;
        const _Float16* q1p = q0p + (size_t)16 * QKVLD;
#pragma unroll
        for (int st = 0; st < 4; st++) {
            aq0[st] = *(const half8*)(q0p + quad * 8 + 32 * st);
            aq1[st] = *(const half8*)(q1p + quad * 8 + 32 * st);
        }
    }

    f32x4 Of0[8], Of1[8];
#pragma unroll
    for (int dt = 0; dt < 8; dt++) {
        Of0[dt] = (f32x4){0.f, 0.f, 0.f, 0.f};
        Of1[dt] = (f32x4){0.f, 0.f, 0.f, 0.f};
    }
    float m_s0 = -1e30f, l_s0 = 0.f;
    float m_s1 = -1e30f, l_s1 = 0.f;

    for (int kt = 0; kt < nkt; ++kt) {
        const int kbase = kt << 6;

        __syncthreads();  // all waves done reading previous tile's LDS
        *(uint4*)&Ks[kr0][ko0]        = kA;
        *(uint4*)&Ks[kr0 + 32][ko0]   = kB;
        *(uint4*)&Vts[vr0][vo0]       = vA;
        *(uint4*)&Vts[vr0 + 64][vo0]  = vB;
        __syncthreads();  // tile visible to all waves

        if (kt + 1 < nkt) ISSUE_LOAD((kt + 1) << 6);

        // whole 32-q wave-tile masked: skip (barriers already passed)
        if (kbase > q0w + 31) continue;

        // QK^T swapped: Sc{g}[s][r] = S[q = q0w+16g+lcol][k = kbase+16s+4quad+r]
        f32x4 Sc0[4], Sc1[4];
#pragma unroll
        for (int s = 0; s < 4; s++) {
            Sc0[s] = (f32x4){0.f, 0.f, 0.f, 0.f};
            Sc1[s] = (f32x4){0.f, 0.f, 0.f, 0.f};
#pragma unroll
            for (int st = 0; st < 4; st++) {
                half8 bk = *(const half8*)&Ks[16 * s + lcol][quad * 8 + 32 * st];
                Sc0[s] = __builtin_amdgcn_mfma_f32_16x16x32_f16(bk, aq0[st], Sc0[s], 0, 0, 0);
                Sc1[s] = __builtin_amdgcn_mfma_f32_16x16x32_f16(bk, aq1[st], Sc1[s], 0, 0, 0);
            }
        }

        if (kbase + 63 > q0w) {  // diagonal region: causal mask per group
#pragma unroll
            for (int s = 0; s < 4; s++)
#pragma unroll
                for (int r = 0; r < 4; r++) {
                    int kk = kbase + 16 * s + quad * 4 + r;
                    if (kk > q0w + lcol)      Sc0[s][r] = -1e30f;
                    if (kk > q0w + 16 + lcol) Sc1[s][r] = -1e30f;
                }
        }

        half8 ap0[2], ap1[2];

        // ---- group 0 softmax + P0 round-trip ----
        {
            float pmax = Sc0[0][0];
#pragma unroll
            for (int s = 0; s < 4; s++)
#pragma unroll
                for (int r = 0; r < 4; r++) pmax = fmaxf(pmax, Sc0[s][r]);
            pmax = fmaxf(pmax, __shfl_xor(pmax, 16));
            pmax = fmaxf(pmax, __shfl_xor(pmax, 32));
            if (!__all(pmax <= m_s0 + 5.0f)) {
                float mnew = fmaxf(m_s0, pmax);
                float alpha = __expf(m_s0 - mnew);
                m_s0 = mnew;
                l_s0 *= alpha;
                float a0 = __shfl(alpha, quad * 4 + 0);
                float a1 = __shfl(alpha, quad * 4 + 1);
                float a2 = __shfl(alpha, quad * 4 + 2);
                float a3 = __shfl(alpha, quad * 4 + 3);
#pragma unroll
                for (int dt = 0; dt < 8; dt++) {
                    Of0[dt][0] *= a0; Of0[dt][1] *= a1;
                    Of0[dt][2] *= a2; Of0[dt][3] *= a3;
                }
            }
            float sum = 0.f;
#pragma unroll
            for (int s = 0; s < 4; s++)
#pragma unroll
                for (int r = 0; r < 4; r++) {
                    float p = __expf(Sc0[s][r] - m_s0);
                    Sc0[s][r] = p;
                    sum += p;
                }
            sum += __shfl_xor(sum, 16);
            sum += __shfl_xor(sum, 32);
            l_s0 += sum;
#pragma unroll
            for (int s = 0; s < 4; s++) {
                half4 pk;
                pk[0] = (_Float16)Sc0[s][0]; pk[1] = (_Float16)Sc0[s][1];
                pk[2] = (_Float16)Sc0[s][2]; pk[3] = (_Float16)Sc0[s][3];
                *(half4*)&Ps[wave][lcol][16 * s + 4 * quad] = pk;
            }
            ap0[0] = *(const half8*)&Ps[wave][lcol][quad * 8];
            ap0[1] = *(const half8*)&Ps[wave][lcol][quad * 8 + 32];
        }

        // ---- group 1 softmax + P1 round-trip (reuses the same Ps slice;
        //      same-wave DS ops to aliasing addresses stay in order) ----
        {
            float pmax = Sc1[0][0];
#pragma unroll
            for (int s = 0; s < 4; s++)
#pragma unroll
                for (int r = 0; r < 4; r++) pmax = fmaxf(pmax, Sc1[s][r]);
            pmax = fmaxf(pmax, __shfl_xor(pmax, 16));
            pmax = fmaxf(pmax, __shfl_xor(pmax, 32));
            if (!__all(pmax <= m_s1 + 5.0f)) {
                float mnew = fmaxf(m_s1, pmax);
                float alpha = __expf(m_s1 - mnew);
                m_s1 = mnew;
                l_s1 *= alpha;
                float a0 = __shfl(alpha, quad * 4 + 0);
                float a1 = __shfl(alpha, quad * 4 + 1);
                float a2 = __shfl(alpha, quad * 4 + 2);
                float a3 = __shfl(alpha, quad * 4 + 3);
#pragma unroll
                for (int dt = 0; dt < 8; dt++) {
                    Of1[dt][0] *= a0; Of1[dt][1] *= a1;
                    Of1[dt][2] *= a2; Of1[dt][3] *= a3;
                }
            }
            float sum = 0.f;
#pragma unroll
            for (int s = 0; s < 4; s++)
#pragma unroll
                for (int r = 0; r < 4; r++) {
                    float p = __expf(Sc1[s][r] - m_s1);
                    Sc1[s][r] = p;
                    sum += p;
                }
            sum += __shfl_xor(sum, 16);
            sum += __shfl_xor(sum, 32);
            l_s1 += sum;
#pragma unroll
            for (int s = 0; s < 4; s++) {
                half4 pk;
                pk[0] = (_Float16)Sc1[s][0]; pk[1] = (_Float16)Sc1[s][1];
                pk[2] = (_Float16)Sc1[s][2]; pk[3] = (_Float16)Sc1[s][3];
                *(half4*)&Ps[wave][lcol][16 * s + 4 * quad] = pk;
            }
            ap1[0] = *(const half8*)&Ps[wave][lcol][quad * 8];
            ap1[1] = *(const half8*)&Ps[wave][lcol][quad * 8 + 32];
        }

        // PV: each bv read feeds BOTH groups (the LDS amortization win)
#pragma unroll
        for (int dt = 0; dt < 8; dt++) {
#pragma unroll
            for (int st = 0; st < 2; st++) {
                half8 bv = *(const half8*)&Vts[16 * dt + lcol][quad * 8 + 32 * st];
                Of0[dt] = __builtin_amdgcn_mfma_f32_16x16x32_f16(
                    st == 0 ? ap0[0] : ap0[1], bv, Of0[dt], 0, 0, 0);
                Of1[dt] = __builtin_amdgcn_mfma_f32_16x16x32_f16(
                    st == 0 ? ap1[0] : ap1[1], bv, Of1[dt], 0, 0, 0);
            }
        }
    }

    // epilogue, per group
    {
        float invl = 1.f / l_s0;
        float i0 = __shfl(invl, quad * 4 + 0);
        float i1 = __shfl(invl, quad * 4 + 1);
        float i2 = __shfl(invl, quad * 4 + 2);
        float i3 = __shfl(invl, quad * 4 + 3);
        _Float16* obase =
            ab + (size_t)(b * SEQ + q0w + quad * 4) * DMODEL + h * HEADDIM;
#pragma unroll
        for (int dt = 0; dt < 8; dt++) {
            obase[(size_t)0 * DMODEL + 16 * dt + lcol] = (_Float16)(Of0[dt][0] * i0);
            obase[(size_t)1 * DMODEL + 16 * dt + lcol] = (_Float16)(Of0[dt][1] * i1);
            obase[(size_t)2 * DMODEL + 16 * dt + lcol] = (_Float16)(Of0[dt][2] * i2);
            obase[(size_t)3 * DMODEL + 16 * dt + lcol] = (_Float16)(Of0[dt][3] * i3);
        }
    }
    {
        float invl = 1.f / l_s1;
        float i0 = __shfl(invl, quad * 4 + 0);
        float i1 = __shfl(invl, quad * 4 + 1);
        float i2 = __shfl(invl, quad * 4 + 2);
        float i3 = __shfl(invl, quad * 4 + 3);
        _Float16* obase =
            ab + (size_t)(b * SEQ + q0w + 16 + quad * 4) * DMODEL + h * HEADDIM;
#pragma unroll
        for (int dt = 0; dt < 8; dt++) {
            obase[(size_t)0 * DMODEL + 16 * dt + lcol] = (_Float16)(Of1[dt][0] * i0);
            obase[(size_t)1 * DMODEL + 16 * dt + lcol] = (_Float16)(Of1[dt][1] * i1);
            obase[(size_t)2 * DMODEL + 16 * dt + lcol] = (_Float16)(Of1[dt][2] * i2);
            obase[(size_t)3 * DMODEL + 16 * dt + lcol] = (_Float16)(Of1[dt][3] * i3);
        }
    }
#undef ISSUE_LOAD
}

// ---------------------------------------------------------------------------
extern "C" void kernel_launch(void* const* d_in, const int* in_sizes, int n_in,
                              void* d_out, int out_size, void* d_ws, size_t ws_size,
                              hipStream_t stream) {
    const float* query = (const float*)d_in[0];
    const float* Wq = (const float*)d_in[1];
    const float* Wk = (const float*)d_in[2];
    const float* Wv = (const float*)d_in[3];
    const float* Wo = (const float*)d_in[4];
    float* out = (float*)d_out;

    const size_t MB = 1024 * 1024;
    char* w = (char*)d_ws;
    _Float16* xh   = (_Float16*)(w + 0 * MB);    // 16 MB f16 query (dead after QKV GEMM)
    _Float16* ab   = (_Float16*)(w + 0 * MB);    // 16 MB f16 attn out (reuses xh slot)
    _Float16* qkvh = (_Float16*)(w + 16 * MB);   // 48 MB f16 fused Q|K|V [M,6144] (V region unused)
    _Float16* Wh3  = (_Float16*)(w + 64 * MB);   // 24 MB f16 weight slot (QKV)
    _Float16* vtb  = (_Float16*)(w + 88 * MB);   // 16 MB f16 V^T [B,H,128,S]
    _Float16* woh  = (_Float16*)(w + 104 * MB);  // 8 MB f16 Wo (only if ws fits)

    const int convW = (DMODEL * DMODEL) / (256 * 8);   // 2048 blocks
    const bool fuseWo = ws_size >= (size_t)112 * MB;

    // all input conversions in one dispatch (query + Wq/Wk/Wv [+ Wo])
    int convBlocks = 4096 + (fuseWo ? 4 : 3) * 2048;
    f2h_multi<<<convBlocks, 256, 0, stream>>>(query, Wq, Wk, Wv, Wo, xh, Wh3, woh);

    // fused QKV projection + rope (Q scaled) + V transpose, one dispatch
    gemm_qkv<<<dim3(QKVLD / 256, MTOT / 256), 512, 0, stream>>>(xh, Wh3, qkvh, vtb);

    attn_mfma<<<dim3(8, NHEADS, BATCH), 512, 0, stream>>>(qkvh, vtb, ab);

    const _Float16* woSrc;
    if (fuseWo) {
        woSrc = woh;          // converted in dispatch 1
    } else {
        f2h_conv<<<convW, 256, 0, stream>>>(Wo, Wh3);  // fallback: late convert
        woSrc = Wh3;
    }
    // Wo: 128^2 tile -> (16,32) = 512 blocks, ~3/CU (full-chip, no half-grid tail)
    gemm_h<false><<<dim3(DMODEL / 128, MTOT / 128), 256, 0, stream>>>(
        ab, woSrc, out, MTOT, DMODEL, DMODEL);
}

// Round 13
// 374.503 us; speedup vs baseline: 1.1207x; 1.0257x over previous
//
#include <hip/hip_runtime.h>
#include <math.h>

// Problem constants
#define BATCH 2
#define SEQ 2048
#define DMODEL 2048
#define NHEADS 16
#define HEADDIM 128
#define MTOT (BATCH * SEQ)   // 4096
#define QKVLD 6144           // fused QKV row stride (Q|K|V)

typedef __attribute__((ext_vector_type(8))) _Float16 half8;  // 8 f16 (4 VGPRs)
typedef __attribute__((ext_vector_type(4))) _Float16 half4;  // 4 f16 (2 VGPRs)
typedef __attribute__((ext_vector_type(4))) float f32x4;     // 4 fp32

// async global -> LDS, 16B per lane (global_load_lds_dwordx4)
__device__ __forceinline__ void gl_lds16(const void* g, void* l) {
    __builtin_amdgcn_global_load_lds(
        (const __attribute__((address_space(1))) unsigned int*)g,
        (__attribute__((address_space(3))) unsigned int*)l, 16, 0, 0);
}

// ---------------------------------------------------------------------------
// fp32 -> f16 convert, 8 elems/thread; query + Wq/Wk/Wv (+ optionally Wo).
// ---------------------------------------------------------------------------
__global__ __launch_bounds__(256) void f2h_multi(const float* __restrict__ query,
                                                 const float* __restrict__ Wq,
                                                 const float* __restrict__ Wk,
                                                 const float* __restrict__ Wv,
                                                 const float* __restrict__ Wo,
                                                 _Float16* __restrict__ xh,
                                                 _Float16* __restrict__ Wh3,
                                                 _Float16* __restrict__ woh) {
    const float* src;
    _Float16* dst;
    size_t i;
    int bx = blockIdx.x;
    if (bx < 4096) {
        src = query; dst = xh;
        i = ((size_t)bx * 256 + threadIdx.x) * 8;
    } else {
        int wi = bx - 4096;
        int y = wi >> 11;           // 0..3
        int off = wi & 2047;
        src = (y == 0) ? Wq : (y == 1) ? Wk : (y == 2) ? Wv : Wo;
        dst = (y == 3) ? woh : Wh3 + (size_t)y * (DMODEL * DMODEL);
        i = ((size_t)off * 256 + threadIdx.x) * 8;
    }
    float4 a = *(const float4*)(src + i);
    float4 b = *(const float4*)(src + i + 4);
    union { uint4 u; _Float16 h[8]; } o;
    o.h[0] = (_Float16)a.x; o.h[1] = (_Float16)a.y;
    o.h[2] = (_Float16)a.z; o.h[3] = (_Float16)a.w;
    o.h[4] = (_Float16)b.x; o.h[5] = (_Float16)b.y;
    o.h[6] = (_Float16)b.z; o.h[7] = (_Float16)b.w;
    *(uint4*)(dst + i) = o.u;
}

// plain single-source convert (fallback for Wo when workspace is tight)
__global__ __launch_bounds__(256) void f2h_conv(const float* __restrict__ src,
                                                _Float16* __restrict__ dst) {
    size_t i = ((size_t)blockIdx.x * 256 + threadIdx.x) * 8;
    float4 a = *(const float4*)(src + i);
    float4 b = *(const float4*)(src + i + 4);
    union { uint4 u; _Float16 h[8]; } o;
    o.h[0] = (_Float16)a.x; o.h[1] = (_Float16)a.y;
    o.h[2] = (_Float16)a.z; o.h[3] = (_Float16)a.w;
    o.h[4] = (_Float16)b.x; o.h[5] = (_Float16)b.y;
    o.h[6] = (_Float16)b.z; o.h[7] = (_Float16)b.w;
    *(uint4*)(dst + i) = o.u;
}

// ---------------------------------------------------------------------------
// 8-phase 256x256 MFMA GEMM with FUSED epilogue (QKV projection only):
//  - Q/K tiles (n0 < 4096): acc -> LDS (K-loop buffers are dead; aliased) ->
//    rope (scale folded for Q) -> coalesced f16 stores to qkv.
//  - V tiles (n0 >= 4096): acc stored DIRECTLY transposed to vtb [B,H,128,S].
// ---------------------------------------------------------------------------
#define SB0  __builtin_amdgcn_sched_barrier(0)
#define BAR  __builtin_amdgcn_s_barrier()
#define VMW4 do { SB0; asm volatile("s_waitcnt vmcnt(4)"); SB0; } while (0)
#define VMW0 do { SB0; asm volatile("s_waitcnt vmcnt(0)"); SB0; } while (0)

__global__ __launch_bounds__(512, 2) void gemm_qkv(const _Float16* __restrict__ A,
                                                   const _Float16* __restrict__ W,
                                                   _Float16* __restrict__ qkv,
                                                   _Float16* __restrict__ vtb) {
    // one raw LDS pool: K-loop double buffers alias the epilogue exchange tile
    __shared__ __align__(16) char lds_raw[131072];
    _Float16 (*LAb)[2][128][64] = (_Float16(*)[2][128][64])lds_raw;           // [2][2][128][64]
    _Float16 (*LBb)[2][128][64] = (_Float16(*)[2][128][64])(lds_raw + 65536); // [2][2][128][64]

    const int K = DMODEL;
    const int tid = threadIdx.x;
    const int lane = tid & 63;
    const int wave = tid >> 6;
    const int quad = lane >> 4;
    const int lcol = lane & 15;
    const int wr = wave >> 2;    // 0..1  (M half)
    const int wc = wave & 3;     // 0..3  (N quarter)
    const int m0 = blockIdx.y * 256;
    const int n0 = blockIdx.x * 256;

    const int srow = tid >> 3;                // 0..63
    const int sc8p = tid & 7;                 // physical 16B chunk (linear LDS)
    const int sc8l = sc8p ^ (srow & 7);       // logical chunk (pre-swizzled src)

#define STA(BUF, HALF, KT)                                                     \
    do {                                                                       \
        _Pragma("unroll") for (int j = 0; j < 2; j++)                          \
            gl_lds16(A + (size_t)(m0 + (HALF)*128 + j*64 + srow) * K +         \
                         (KT)*64 + sc8l*8,                                     \
                     &LAb[BUF][HALF][j*64 + srow][sc8p*8]);                    \
    } while (0)
#define STB(BUF, HALF, KT)                                                     \
    do {                                                                       \
        _Pragma("unroll") for (int j = 0; j < 2; j++)                          \
            gl_lds16(W + (size_t)(n0 + (HALF)*128 + j*64 + srow) * K +         \
                         (KT)*64 + sc8l*8,                                     \
                     &LBb[BUF][HALF][j*64 + srow][sc8p*8]);                    \
    } while (0)

    auto rdA = [&](int buf, int mf, int ks) -> half8 {
        int R = mf * 16 + lcol;
        return *(const half8*)&LAb[buf][wr][R]
                [(ks * 32 + quad * 8) ^ ((lcol & 7) << 3)];
    };
    auto rdB = [&](int buf, int nf, int ks) -> half8 {
        int R = (wc & 1) * 64 + nf * 16 + lcol;
        return *(const half8*)&LBb[buf][wc >> 1][R]
                [(ks * 32 + quad * 8) ^ ((lcol & 7) << 3)];
    };

    f32x4 acc[8][4];
#pragma unroll
    for (int i = 0; i < 8; i++)
#pragma unroll
        for (int j = 0; j < 4; j++) acc[i][j] = (f32x4){0.f, 0.f, 0.f, 0.f};

#define KTILE4(BUF, S1, S2, S3, S4, W4)                                        \
    {                                                                          \
        half8 a[4][2], b[4][2];                                                \
        _Pragma("unroll") for (int mf = 0; mf < 4; mf++)                       \
            _Pragma("unroll") for (int ks = 0; ks < 2; ks++)                   \
                a[mf][ks] = rdA(BUF, mf, ks);                                  \
        _Pragma("unroll") for (int nf = 0; nf < 2; nf++)                       \
            _Pragma("unroll") for (int ks = 0; ks < 2; ks++)                   \
                b[nf][ks] = rdB(BUF, nf, ks);                                  \
        S1; SB0; BAR; SB0;                                                     \
        __builtin_amdgcn_s_setprio(1);                                         \
        _Pragma("unroll") for (int ks = 0; ks < 2; ks++)                       \
            _Pragma("unroll") for (int mf = 0; mf < 4; mf++)                   \
                _Pragma("unroll") for (int nf = 0; nf < 2; nf++)               \
                    acc[mf][nf] = __builtin_amdgcn_mfma_f32_16x16x32_f16(      \
                        a[mf][ks], b[nf][ks], acc[mf][nf], 0, 0, 0);           \
        __builtin_amdgcn_s_setprio(0); SB0; BAR; SB0;                          \
        _Pragma("unroll") for (int nf = 0; nf < 2; nf++)                       \
            _Pragma("unroll") for (int ks = 0; ks < 2; ks++)                   \
                b[2 + nf][ks] = rdB(BUF, 2 + nf, ks);                          \
        S2; SB0; BAR; SB0;                                                     \
        __builtin_amdgcn_s_setprio(1);                                         \
        _Pragma("unroll") for (int ks = 0; ks < 2; ks++)                       \
            _Pragma("unroll") for (int mf = 0; mf < 4; mf++)                   \
                _Pragma("unroll") for (int nf = 0; nf < 2; nf++)               \
                    acc[mf][2 + nf] = __builtin_amdgcn_mfma_f32_16x16x32_f16(  \
                        a[mf][ks], b[2 + nf][ks], acc[mf][2 + nf], 0, 0, 0);   \
        __builtin_amdgcn_s_setprio(0); SB0; BAR; SB0;                          \
        _Pragma("unroll") for (int mf = 0; mf < 4; mf++)                       \
            _Pragma("unroll") for (int ks = 0; ks < 2; ks++)                   \
                a[mf][ks] = rdA(BUF, 4 + mf, ks);                              \
        S3; SB0; BAR; SB0;                                                     \
        __builtin_amdgcn_s_setprio(1);                                         \
        _Pragma("unroll") for (int ks = 0; ks < 2; ks++)                       \
            _Pragma("unroll") for (int mf = 0; mf < 4; mf++)                   \
                _Pragma("unroll") for (int nf = 0; nf < 2; nf++)               \
                    acc[4 + mf][nf] = __builtin_amdgcn_mfma_f32_16x16x32_f16(  \
                        a[mf][ks], b[nf][ks], acc[4 + mf][nf], 0, 0, 0);       \
        __builtin_amdgcn_s_setprio(0); SB0; BAR; SB0;                          \
        S4; W4; BAR; SB0;                                                      \
        __builtin_amdgcn_s_setprio(1);                                         \
        _Pragma("unroll") for (int ks = 0; ks < 2; ks++)                       \
            _Pragma("unroll") for (int mf = 0; mf < 4; mf++)                   \
                _Pragma("unroll") for (int nf = 0; nf < 2; nf++)               \
                    acc[4 + mf][2 + nf] =                                      \
                        __builtin_amdgcn_mfma_f32_16x16x32_f16(                \
                            a[mf][ks], b[2 + nf][ks], acc[4 + mf][2 + nf],     \
                            0, 0, 0);                                          \
        __builtin_amdgcn_s_setprio(0); SB0; BAR; SB0;                          \
    }

    STB(0, 0, 0); STB(0, 1, 0); STA(0, 0, 0); STA(0, 1, 0);
    STB(1, 0, 1); STB(1, 1, 1);
    VMW4; BAR; SB0;

    const int niter = K >> 7;  // K/128 (2 K-tiles per iteration)
    for (int i = 0; i < niter - 1; ++i) {
        const int t0 = 2 * i;
        KTILE4(0, STA(1, 0, t0 + 1), STA(1, 1, t0 + 1),
                  STB(0, 0, t0 + 2), STB(0, 1, t0 + 2), VMW4);
        KTILE4(1, STA(0, 0, t0 + 2), STA(0, 1, t0 + 2),
                  STB(1, 0, t0 + 3), STB(1, 1, t0 + 3), VMW4);
    }
    {
        const int t0 = 2 * (niter - 1);
        KTILE4(0, STA(1, 0, t0 + 1), STA(1, 1, t0 + 1),
                  (void)0, (void)0, VMW0);
        KTILE4(1, (void)0, (void)0, (void)0, (void)0, (void)0);
    }

    // ---------------- fused epilogue ----------------
    if (n0 < 2 * DMODEL) {
        // Q or K tile: rope via LDS exchange (pairs (d, d+64) live in
        // different waves' accumulators). K-loop LDS is dead; alias it.
        const float scale = (n0 < DMODEL) ? 0.08838834764831845f : 1.0f;
        _Float16 (*T)[256] = (_Float16(*)[256])lds_raw;

        __syncthreads();  // all waves past their last LDS read of the K-loop
#pragma unroll
        for (int mf = 0; mf < 8; mf++)
#pragma unroll
            for (int nf = 0; nf < 4; nf++)
#pragma unroll
                for (int r = 0; r < 4; r++)
                    T[wr * 128 + mf * 16 + quad * 4 + r]
                     [wc * 64 + nf * 16 + lcol] = (_Float16)acc[mf][nf][r];
        __syncthreads();

        // 4096 (row, head-half, chunk) units; 8 per thread.
#pragma unroll
        for (int u = 0; u < 8; ++u) {
            int unit = tid + 512 * u;
            int row = unit >> 4;              // 0..255
            int hh = (unit >> 3) & 1;         // which head in this tile
            int c8 = (unit & 7) * 8;          // first-half d chunk
            int s = (m0 + row) & (SEQ - 1);
            int cb = hh * 128 + c8;
            half8 x1v = *(const half8*)&T[row][cb];
            half8 x2v = *(const half8*)&T[row][cb + 64];
            half8 o1v, o2v;
#pragma unroll
            for (int j = 0; j < 8; j++) {
                float inv = __expf(-(float)(c8 + j) * 0.14391156831212787f);
                float f = (float)s * inv;
                float sn, cs;
                __sincosf(f, &sn, &cs);
                float x1 = (float)x1v[j];
                float x2 = (float)x2v[j];
                o1v[j] = (_Float16)((x1 * cs - x2 * sn) * scale);
                o2v[j] = (_Float16)((x2 * cs + x1 * sn) * scale);
            }
            _Float16* g = qkv + (size_t)(m0 + row) * QKVLD + n0 + cb;
            *(half8*)g = o1v;
            *(half8*)(g + 64) = o2v;
        }
    } else {
        // V tile: direct transposed store to vtb [B,H,128,S]
        const int vbase = n0 - 2 * DMODEL;
#pragma unroll
        for (int mf = 0; mf < 8; mf++) {
            int m = m0 + wr * 128 + mf * 16 + quad * 4;
            int b = m >> 11;
            int s = m & (SEQ - 1);
#pragma unroll
            for (int nf = 0; nf < 4; nf++) {
                int col = vbase + wc * 64 + nf * 16 + lcol;
                int hh = col >> 7;
                int d = col & 127;
                half4 pk;
                pk[0] = (_Float16)acc[mf][nf][0];
                pk[1] = (_Float16)acc[mf][nf][1];
                pk[2] = (_Float16)acc[mf][nf][2];
                pk[3] = (_Float16)acc[mf][nf][3];
                *(half4*)(vtb +
                          ((size_t)((b * NHEADS + hh) * HEADDIM + d)) * SEQ + s) = pk;
            }
        }
    }
#undef KTILE4
#undef STA
#undef STB
}

// ---------------------------------------------------------------------------
// 128x128 2-barrier MFMA GEMM (for Wo: full-chip grid, 3 blocks/CU)
// ---------------------------------------------------------------------------
template <bool F16OUT>
__global__ __launch_bounds__(256) void gemm_h(const _Float16* __restrict__ A,
                                              const _Float16* __restrict__ W,
                                              void* __restrict__ Cout,
                                              int M, int N, int K) {
    __shared__ __align__(16) _Float16 As[128 * 32];
    __shared__ __align__(16) _Float16 Bs[128 * 32];

    const int tid = threadIdx.x;
    const int wv = tid >> 6;
    const int ln = tid & 63;
    const int quad = ln >> 4;
    const int lcol = ln & 15;
    const int m0 = blockIdx.y * 128;
    const int n0 = blockIdx.x * 128;
    const int wm = (wv >> 1) * 64;
    const int wn = (wv & 1) * 64;

    const int srow = ln >> 2;
    const int kblk = (ln & 3) * 8;

    f32x4 acc[4][4];
#pragma unroll
    for (int i = 0; i < 4; i++)
#pragma unroll
        for (int j = 0; j < 4; j++) acc[i][j] = (f32x4){0.f, 0.f, 0.f, 0.f};

    for (int k0 = 0; k0 < K; k0 += 32) {
        __syncthreads();
#pragma unroll
        for (int j = 0; j < 2; j++) {
            int r = wv * 32 + j * 16 + srow;
            gl_lds16(A + (size_t)(m0 + r) * K + k0 + kblk, &As[r * 32 + kblk]);
            gl_lds16(W + (size_t)(n0 + r) * K + k0 + kblk, &Bs[r * 32 + kblk]);
        }
        __syncthreads();

        half8 af[4], bf[4];
#pragma unroll
        for (int ms = 0; ms < 4; ms++)
            af[ms] = *(const half8*)&As[(wm + ms * 16 + lcol) * 32 + quad * 8];
#pragma unroll
        for (int ns = 0; ns < 4; ns++)
            bf[ns] = *(const half8*)&Bs[(wn + ns * 16 + lcol) * 32 + quad * 8];
#pragma unroll
        for (int ms = 0; ms < 4; ms++)
#pragma unroll
            for (int ns = 0; ns < 4; ns++)
                acc[ms][ns] = __builtin_amdgcn_mfma_f32_16x16x32_f16(
                    af[ms], bf[ns], acc[ms][ns], 0, 0, 0);
    }

    float* Cf = (float*)Cout;
    _Float16* Ch = (_Float16*)Cout;
#pragma unroll
    for (int ms = 0; ms < 4; ms++)
#pragma unroll
        for (int ns = 0; ns < 4; ns++)
#pragma unroll
            for (int r = 0; r < 4; r++) {
                size_t row = m0 + wm + ms * 16 + quad * 4 + r;
                size_t col = n0 + wn + ns * 16 + lcol;
                if (F16OUT)
                    Ch[row * N + col] = (_Float16)acc[ms][ns][r];
                else
                    Cf[row * N + col] = acc[ms][ns][r];
            }
}

// ---------------------------------------------------------------------------
// Flash causal attention, f16 MFMA, swapped-QK^T in-register softmax.
// 32 q-rows per wave (two 16-q groups sharing each K/V LDS read).
// NEW (R13): K/V LDS double-buffered -> ONE barrier per k-iteration.
// iter t writes buf[t&1]; the iter t-1 barrier separates iter t-2's reads
// of buf[t&1] from iter t's writes (all waves' program order crosses it).
// LDS 88 KB, still 1 block/CU. grid (8, H, B), 512 threads.
// ---------------------------------------------------------------------------
__global__ __launch_bounds__(512) void attn_mfma(const _Float16* __restrict__ qkv,
                                                 const _Float16* __restrict__ vtb,
                                                 _Float16* __restrict__ ab) {
    __shared__ __align__(16) _Float16 Ks[2][64][136];    // 34.8 KB
    __shared__ __align__(16) _Float16 Vts[2][128][72];   // 36.9 KB
    __shared__ __align__(16) _Float16 Ps[8][16][72];     // 18.4 KB

    const int tid = threadIdx.x;
    const int wave = tid >> 6;      // 0..7
    const int lane = tid & 63;
    const int quad = lane >> 4;
    const int lcol = lane & 15;

    const int h = blockIdx.y;
    const int b = blockIdx.z;
    const int qtA = blockIdx.x;     // 0..7 ; high tile is 15-qtA

    const int wtile = (wave < 4) ? qtA : (15 - qtA);
    const int q0w = wtile * 128 + (wave & 3) * 32;   // this wave's 32 q-rows
    const int nkt = 2 * (15 - qtA) + 2;              // block-uniform

    const int kr0 = tid >> 4;             // 0..31 (second chunk: +32)
    const int ko0 = (tid & 15) * 8;       // 0..120
    const int vr0 = tid >> 3;             // 0..63 (second chunk: +64)
    const int vo0 = (tid & 7) * 8;        // 0..56

    const _Float16* kbp = qkv + (size_t)b * SEQ * QKVLD + DMODEL + h * HEADDIM;
    const _Float16* vbp = vtb + ((size_t)(b * NHEADS + h) * HEADDIM) * SEQ;

    uint4 kA, kB, vA, vB;
#define ISSUE_LOAD(kb)                                                        \
    do {                                                                      \
        int _kb = (kb);                                                       \
        kA = *(const uint4*)(kbp + (size_t)(_kb + kr0) * QKVLD + ko0);        \
        kB = *(const uint4*)(kbp + (size_t)(_kb + 32 + kr0) * QKVLD + ko0);   \
        vA = *(const uint4*)(vbp + (size_t)vr0 * SEQ + _kb + vo0);            \
        vB = *(const uint4*)(vbp + (size_t)(vr0 + 64) * SEQ + _kb + vo0);     \
    } while (0)

    ISSUE_LOAD(0);

    // Q for both 16-q groups
    half8 aq0[4], aq1[4];
    {
        const _Float16* q0p = qkv + (size_t)(b * SEQ + q0w + lcol) * QKVLD + h * HEADDIM;
        const _Float16* q1p = q0p + (size_t)16 * QKVLD;
#pragma unroll
        for (int st = 0; st < 4; st++) {
            aq0[st] = *(const half8*)(q0p + quad * 8 + 32 * st);
            aq1[st] = *(const half8*)(q1p + quad * 8 + 32 * st);
        }
    }

    f32x4 Of0[8], Of1[8];
#pragma unroll
    for (int dt = 0; dt < 8; dt++) {
        Of0[dt] = (f32x4){0.f, 0.f, 0.f, 0.f};
        Of1[dt] = (f32x4){0.f, 0.f, 0.f, 0.f};
    }
    float m_s0 = -1e30f, l_s0 = 0.f;
    float m_s1 = -1e30f, l_s1 = 0.f;

    for (int kt = 0; kt < nkt; ++kt) {
        const int kbase = kt << 6;
        const int cur = kt & 1;

        // write this tile into its buffer; iter (kt-1)'s barrier already
        // separated these writes from iter (kt-2)'s reads of buf[cur]
        *(uint4*)&Ks[cur][kr0][ko0]        = kA;
        *(uint4*)&Ks[cur][kr0 + 32][ko0]   = kB;
        *(uint4*)&Vts[cur][vr0][vo0]       = vA;
        *(uint4*)&Vts[cur][vr0 + 64][vo0]  = vB;
        __syncthreads();  // single barrier: tile visible to all waves

        if (kt + 1 < nkt) ISSUE_LOAD((kt + 1) << 6);

        // whole 32-q wave-tile masked: skip (barrier already passed)
        if (kbase > q0w + 31) continue;

        // QK^T swapped: Sc{g}[s][r] = S[q = q0w+16g+lcol][k = kbase+16s+4quad+r]
        f32x4 Sc0[4], Sc1[4];
#pragma unroll
        for (int s = 0; s < 4; s++) {
            Sc0[s] = (f32x4){0.f, 0.f, 0.f, 0.f};
            Sc1[s] = (f32x4){0.f, 0.f, 0.f, 0.f};
#pragma unroll
            for (int st = 0; st < 4; st++) {
                half8 bk = *(const half8*)&Ks[cur][16 * s + lcol][quad * 8 + 32 * st];
                Sc0[s] = __builtin_amdgcn_mfma_f32_16x16x32_f16(bk, aq0[st], Sc0[s], 0, 0, 0);
                Sc1[s] = __builtin_amdgcn_mfma_f32_16x16x32_f16(bk, aq1[st], Sc1[s], 0, 0, 0);
            }
        }

        if (kbase + 63 > q0w) {  // diagonal region: causal mask per group
#pragma unroll
            for (int s = 0; s < 4; s++)
#pragma unroll
                for (int r = 0; r < 4; r++) {
                    int kk = kbase + 16 * s + quad * 4 + r;
                    if (kk > q0w + lcol)      Sc0[s][r] = -1e30f;
                    if (kk > q0w + 16 + lcol) Sc1[s][r] = -1e30f;
                }
        }

        half8 ap0[2], ap1[2];

        // ---- group 0 softmax + P0 round-trip ----
        {
            float pmax = Sc0[0][0];
#pragma unroll
            for (int s = 0; s < 4; s++)
#pragma unroll
                for (int r = 0; r < 4; r++) pmax = fmaxf(pmax, Sc0[s][r]);
            pmax = fmaxf(pmax, __shfl_xor(pmax, 16));
            pmax = fmaxf(pmax, __shfl_xor(pmax, 32));
            if (!__all(pmax <= m_s0 + 5.0f)) {
                float mnew = fmaxf(m_s0, pmax);
                float alpha = __expf(m_s0 - mnew);
                m_s0 = mnew;
                l_s0 *= alpha;
                float a0 = __shfl(alpha, quad * 4 + 0);
                float a1 = __shfl(alpha, quad * 4 + 1);
                float a2 = __shfl(alpha, quad * 4 + 2);
                float a3 = __shfl(alpha, quad * 4 + 3);
#pragma unroll
                for (int dt = 0; dt < 8; dt++) {
                    Of0[dt][0] *= a0; Of0[dt][1] *= a1;
                    Of0[dt][2] *= a2; Of0[dt][3] *= a3;
                }
            }
            float sum = 0.f;
#pragma unroll
            for (int s = 0; s < 4; s++)
#pragma unroll
                for (int r = 0; r < 4; r++) {
                    float p = __expf(Sc0[s][r] - m_s0);
                    Sc0[s][r] = p;
                    sum += p;
                }
            sum += __shfl_xor(sum, 16);
            sum += __shfl_xor(sum, 32);
            l_s0 += sum;
#pragma unroll
            for (int s = 0; s < 4; s++) {
                half4 pk;
                pk[0] = (_Float16)Sc0[s][0]; pk[1] = (_Float16)Sc0[s][1];
                pk[2] = (_Float16)Sc0[s][2]; pk[3] = (_Float16)Sc0[s][3];
                *(half4*)&Ps[wave][lcol][16 * s + 4 * quad] = pk;
            }
            ap0[0] = *(const half8*)&Ps[wave][lcol][quad * 8];
            ap0[1] = *(const half8*)&Ps[wave][lcol][quad * 8 + 32];
        }

        // ---- group 1 softmax + P1 round-trip (reuses the same Ps slice;
        //      same-wave DS ops to aliasing addresses stay in order) ----
        {
            float pmax = Sc1[0][0];
#pragma unroll
            for (int s = 0; s < 4; s++)
#pragma unroll
                for (int r = 0; r < 4; r++) pmax = fmaxf(pmax, Sc1[s][r]);
            pmax = fmaxf(pmax, __shfl_xor(pmax, 16));
            pmax = fmaxf(pmax, __shfl_xor(pmax, 32));
            if (!__all(pmax <= m_s1 + 5.0f)) {
                float mnew = fmaxf(m_s1, pmax);
                float alpha = __expf(m_s1 - mnew);
                m_s1 = mnew;
                l_s1 *= alpha;
                float a0 = __shfl(alpha, quad * 4 + 0);
                float a1 = __shfl(alpha, quad * 4 + 1);
                float a2 = __shfl(alpha, quad * 4 + 2);
                float a3 = __shfl(alpha, quad * 4 + 3);
#pragma unroll
                for (int dt = 0; dt < 8; dt++) {
                    Of1[dt][0] *= a0; Of1[dt][1] *= a1;
                    Of1[dt][2] *= a2; Of1[dt][3] *= a3;
                }
            }
            float sum = 0.f;
#pragma unroll
            for (int s = 0; s < 4; s++)
#pragma unroll
                for (int r = 0; r < 4; r++) {
                    float p = __expf(Sc1[s][r] - m_s1);
                    Sc1[s][r] = p;
                    sum += p;
                }
            sum += __shfl_xor(sum, 16);
            sum += __shfl_xor(sum, 32);
            l_s1 += sum;
#pragma unroll
            for (int s = 0; s < 4; s++) {
                half4 pk;
                pk[0] = (_Float16)Sc1[s][0]; pk[1] = (_Float16)Sc1[s][1];
                pk[2] = (_Float16)Sc1[s][2]; pk[3] = (_Float16)Sc1[s][3];
                *(half4*)&Ps[wave][lcol][16 * s + 4 * quad] = pk;
            }
            ap1[0] = *(const half8*)&Ps[wave][lcol][quad * 8];
            ap1[1] = *(const half8*)&Ps[wave][lcol][quad * 8 + 32];
        }

        // PV: each bv read feeds BOTH groups (the LDS amortization win)
#pragma unroll
        for (int dt = 0; dt < 8; dt++) {
#pragma unroll
            for (int st = 0; st < 2; st++) {
                half8 bv = *(const half8*)&Vts[cur][16 * dt + lcol][quad * 8 + 32 * st];
                Of0[dt] = __builtin_amdgcn_mfma_f32_16x16x32_f16(
                    st == 0 ? ap0[0] : ap0[1], bv, Of0[dt], 0, 0, 0);
                Of1[dt] = __builtin_amdgcn_mfma_f32_16x16x32_f16(
                    st == 0 ? ap1[0] : ap1[1], bv, Of1[dt], 0, 0, 0);
            }
        }
    }

    // epilogue, per group
    {
        float invl = 1.f / l_s0;
        float i0 = __shfl(invl, quad * 4 + 0);
        float i1 = __shfl(invl, quad * 4 + 1);
        float i2 = __shfl(invl, quad * 4 + 2);
        float i3 = __shfl(invl, quad * 4 + 3);
        _Float16* obase =
            ab + (size_t)(b * SEQ + q0w + quad * 4) * DMODEL + h * HEADDIM;
#pragma unroll
        for (int dt = 0; dt < 8; dt++) {
            obase[(size_t)0 * DMODEL + 16 * dt + lcol] = (_Float16)(Of0[dt][0] * i0);
            obase[(size_t)1 * DMODEL + 16 * dt + lcol] = (_Float16)(Of0[dt][1] * i1);
            obase[(size_t)2 * DMODEL + 16 * dt + lcol] = (_Float16)(Of0[dt][2] * i2);
            obase[(size_t)3 * DMODEL + 16 * dt + lcol] = (_Float16)(Of0[dt][3] * i3);
        }
    }
    {
        float invl = 1.f / l_s1;
        float i0 = __shfl(invl, quad * 4 + 0);
        float i1 = __shfl(invl, quad * 4 + 1);
        float i2 = __shfl(invl, quad * 4 + 2);
        float i3 = __shfl(invl, quad * 4 + 3);
        _Float16* obase =
            ab + (size_t)(b * SEQ + q0w + 16 + quad * 4) * DMODEL + h * HEADDIM;
#pragma unroll
        for (int dt = 0; dt < 8; dt++) {
            obase[(size_t)0 * DMODEL + 16 * dt + lcol] = (_Float16)(Of1[dt][0] * i0);
            obase[(size_t)1 * DMODEL + 16 * dt + lcol] = (_Float16)(Of1[dt][1] * i1);
            obase[(size_t)2 * DMODEL + 16 * dt + lcol] = (_Float16)(Of1[dt][2] * i2);
            obase[(size_t)3 * DMODEL + 16 * dt + lcol] = (_Float16)(Of1[dt][3] * i3);
        }
    }
#undef ISSUE_LOAD
}

// ---------------------------------------------------------------------------
extern "C" void kernel_launch(void* const* d_in, const int* in_sizes, int n_in,
                              void* d_out, int out_size, void* d_ws, size_t ws_size,
                              hipStream_t stream) {
    const float* query = (const float*)d_in[0];
    const float* Wq = (const float*)d_in[1];
    const float* Wk = (const float*)d_in[2];
    const float* Wv = (const float*)d_in[3];
    const float* Wo = (const float*)d_in[4];
    float* out = (float*)d_out;

    const size_t MB = 1024 * 1024;
    char* w = (char*)d_ws;
    _Float16* xh   = (_Float16*)(w + 0 * MB);    // 16 MB f16 query (dead after QKV GEMM)
    _Float16* ab   = (_Float16*)(w + 0 * MB);    // 16 MB f16 attn out (reuses xh slot)
    _Float16* qkvh = (_Float16*)(w + 16 * MB);   // 48 MB f16 fused Q|K|V [M,6144] (V region unused)
    _Float16* Wh3  = (_Float16*)(w + 64 * MB);   // 24 MB f16 weight slot (QKV)
    _Float16* vtb  = (_Float16*)(w + 88 * MB);   // 16 MB f16 V^T [B,H,128,S]
    _Float16* woh  = (_Float16*)(w + 104 * MB);  // 8 MB f16 Wo (only if ws fits)

    const int convW = (DMODEL * DMODEL) / (256 * 8);   // 2048 blocks
    const bool fuseWo = ws_size >= (size_t)112 * MB;

    // all input conversions in one dispatch (query + Wq/Wk/Wv [+ Wo])
    int convBlocks = 4096 + (fuseWo ? 4 : 3) * 2048;
    f2h_multi<<<convBlocks, 256, 0, stream>>>(query, Wq, Wk, Wv, Wo, xh, Wh3, woh);

    // fused QKV projection + rope (Q scaled) + V transpose, one dispatch
    gemm_qkv<<<dim3(QKVLD / 256, MTOT / 256), 512, 0, stream>>>(xh, Wh3, qkvh, vtb);

    attn_mfma<<<dim3(8, NHEADS, BATCH), 512, 0, stream>>>(qkvh, vtb, ab);

    const _Float16* woSrc;
    if (fuseWo) {
        woSrc = woh;          // converted in dispatch 1
    } else {
        f2h_conv<<<convW, 256, 0, stream>>>(Wo, Wh3);  // fallback: late convert
        woSrc = Wh3;
    }
    // Wo: 128^2 tile -> (16,32) = 512 blocks, ~3/CU (full-chip, no half-grid tail)
    gemm_h<false><<<dim3(DMODEL / 128, MTOT / 128), 256, 0, stream>>>(
        ab, woSrc, out, MTOT, DMODEL, DMODEL);
}